// Round 6
// baseline (3467.664 us; speedup 1.0000x reference)
//
#include <hip/hip_runtime.h>
#include <math.h>

// Problem constants
#define BB 8
#define CC 2048
#define DD 64
#define LL 3
#define HH 4
#define DHH 16
#define KPAD 40   // halves per LDS row: 32 keys + 8 pad (80B = 16B-aligned)

typedef _Float16 half8 __attribute__((ext_vector_type(8)));
typedef float f32x4 __attribute__((ext_vector_type(4)));

#if defined(__has_builtin)
#if __has_builtin(__builtin_amdgcn_exp2f)
#define EXP2F(x) __builtin_amdgcn_exp2f(x)
#else
#define EXP2F(x) __expf((x) * 0.693147180559945f)
#endif
#else
#define EXP2F(x) __expf((x) * 0.693147180559945f)
#endif

// ---------------- exact GELU via A&S 7.1.26 erf (residual-path kernels) ----------------
__device__ __forceinline__ float gelu_f(float x) {
    float z  = 0.70710678118654752f * x;
    float az = fabsf(z);
    float t  = __builtin_amdgcn_rcpf(fmaf(0.3275911f, az, 1.0f));
    float p  = t * fmaf(t, fmaf(t, fmaf(t, fmaf(t, 1.061405429f, -1.453152027f),
                                        1.421413741f), -0.284496736f), 0.254829592f);
    float e  = __expf(-z * z);
    float r  = p * e;                                // erfc(|z|)
    float phi = (x >= 0.0f) ? fmaf(-0.5f, r, 1.0f) : 0.5f * r;
    return x * phi;
}

// ---------------- tanh-form GELU (score path only; max |err| ~3e-4) ----------------
__device__ __forceinline__ float gelu_fast(float x) {
    float x2 = x * x;
    float f  = fmaf(-0.10294357f, x2, -2.30221895f); // -log2e*1.59577*(1+0.044715x^2)
    float e  = EXP2F(x * f);                          // exp(-1.59577(x+0.044715x^3))
    return x * __builtin_amdgcn_rcpf(1.0f + e);
}

__device__ __forceinline__ float wave_sum64(float v) {
    #pragma unroll
    for (int off = 32; off; off >>= 1) v += __shfl_xor(v, off, 64);
    return v;
}

// ---------------- binding encoder ----------------
__global__ __launch_bounds__(256) void k_binding(const float* __restrict__ x,
                                                 const float* __restrict__ role,
                                                 const float* __restrict__ fw,
                                                 float* __restrict__ h) {
    int idx = blockIdx.x * 256 + threadIdx.x;        // B*C*D = 1048576
    int d  = idx & 63;
    int bc = idx >> 6;
    float xl = log1pf(fmaxf(x[bc], 0.0f));
    float f  = gelu_f(xl * fw[d]);
    h[idx] = role[(bc & (CC - 1)) * DD + d] * f;
}

// ---------------- QKV projection + Aq (=qp+b1) precompute ----------------
__global__ __launch_bounds__(256) void k_qkv(const float* __restrict__ h,
                                             const float* __restrict__ qw, const float* __restrict__ qb,
                                             const float* __restrict__ kw, const float* __restrict__ kb,
                                             const float* __restrict__ vw, const float* __restrict__ vb,
                                             const float* __restrict__ w1, const float* __restrict__ b1,
                                             float* __restrict__ Q, float* __restrict__ K,
                                             float* __restrict__ V, float* __restrict__ A) {
    __shared__ __attribute__((aligned(16))) float hrow[4][64];
    __shared__ float qrow[4][64];
    int r  = threadIdx.x >> 6;
    int j  = threadIdx.x & 63;
    int bc = blockIdx.x * 4 + r;                     // 0..16383
    hrow[r][j] = h[(size_t)bc * 64 + j];
    __syncthreads();
    float aq = qb[j], ak = kb[j], av = vb[j];
    const float4* hr4 = (const float4*)hrow[r];
    const float4* qw4 = (const float4*)(qw + j * 64);
    const float4* kw4 = (const float4*)(kw + j * 64);
    const float4* vw4 = (const float4*)(vw + j * 64);
    #pragma unroll
    for (int i = 0; i < 16; ++i) {
        float4 hv = hr4[i];
        float4 a = qw4[i], b = kw4[i], c = vw4[i];
        aq = fmaf(hv.x, a.x, fmaf(hv.y, a.y, fmaf(hv.z, a.z, fmaf(hv.w, a.w, aq))));
        ak = fmaf(hv.x, b.x, fmaf(hv.y, b.y, fmaf(hv.z, b.z, fmaf(hv.w, b.w, ak))));
        av = fmaf(hv.x, c.x, fmaf(hv.y, c.y, fmaf(hv.z, c.z, fmaf(hv.w, c.w, av))));
    }
    int head = j >> 4, dh = j & 15;
    int b = bc >> 11, c = bc & (CC - 1);
    size_t o = ((size_t)(b * HH + head) * CC + c) * DHH + dh;
    Q[o] = aq; K[o] = ak; V[o] = av;
    qrow[r][j] = aq;
    __syncthreads();
    float aA = b1[dh];
    #pragma unroll
    for (int i = 0; i < 16; ++i)
        aA = fmaf(qrow[r][head * 16 + i], w1[dh * 48 + i], aA);
    A[o] = aA;
}

// ---------------- MFMA attention with MLP scores, key-split x2 ----------------
// grid: qt(32) x bh(32) x ks(2) = 2048 blocks (8/CU for cross-wave trans/VALU overlap),
// 4 waves/block, 16 q/wave. Math identical to round 5 (verified); only the key loop
// is halved and O/Dn partials go to ws for a combine pass.
__global__ __launch_bounds__(256, 6) void k_attn(const float* __restrict__ Q, const float* __restrict__ K,
                                                 const float* __restrict__ V, const float* __restrict__ A,
                                                 const float* __restrict__ w1g, const float* __restrict__ w2g,
                                                 float* __restrict__ PO, float* __restrict__ PDn) {
    __shared__ __attribute__((aligned(16))) _Float16 Kl[32 * KPAD];   // [key][i0..15,16=1,17..=0]
    __shared__ __attribute__((aligned(16))) _Float16 Vt[16 * KPAD];   // [d][key]
    __shared__ __attribute__((aligned(16))) _Float16 El[4][16 * KPAD];// per wave [q][key]

    int tid  = threadIdx.x;
    int lane = tid & 63;
    int w    = tid >> 6;
    int quad = lane >> 4;
    int l15  = lane & 15;
    int qt = blockIdx.x & 31;
    int bh = (blockIdx.x >> 5) & 31;
    int ks = blockIdx.x >> 10;
    size_t base = (size_t)bh * (CC * DHH);
    int qbase = qt * 64 + w * 16;

    // one-time constant region of Kl: [16]=1.0, [17..39]=0 per key row
    for (int idx = tid; idx < 32 * 24; idx += 256) {
        int row = idx / 24, off = 16 + idx % 24;
        Kl[row * KPAD + off] = (off == 16) ? (_Float16)1.0f : (_Float16)0.0f;
    }

    // per-lane w2 for rows j = quad*4+r, with 1/sqrt(16)*log2(e) folded (softmax in base 2)
    float w2q[4];
    #pragma unroll
    for (int r = 0; r < 4; ++r) w2q[r] = w2g[quad * 4 + r] * (0.25f * 1.44269504f);

    bool sel_hi = (lane & 16) != 0;                  // quads 1,3 -> sub1 value at store

    // W1k/W1qk slices are q-invariant: hoist to registers (per-lane j=l15, i=quad*8+jj)
    float wk[8], wqk[8];
    #pragma unroll
    for (int jj = 0; jj < 8; ++jj) {
        int i = (quad & 1) * 8 + jj;
        wk[jj]  = w1g[l15 * 48 + 16 + ((quad < 2) ? quad * 8 + jj : i)];
        wqk[jj] = w1g[l15 * 48 + 32 + ((quad < 2) ? quad * 8 + jj : i)];
    }

    // Bq A-frags: m=j=lane&15, kdim=i=quad*8+jj. quads0,1: W1qk[j][i]*q[i]+W1k[j][i];
    // quad2 jj=0: Aq[j]; else 0. 16 frags (64 regs) live across the K loop.
    half8 bq[16];
    {
        int j = l15;
        #pragma unroll
        for (int q = 0; q < 16; ++q) {
            const float* qv = Q + base + (size_t)(qbase + q) * 16;
            float aqv = A[base + (size_t)(qbase + q) * 16 + j];
            half8 v;
            #pragma unroll
            for (int jj = 0; jj < 8; ++jj) {
                float val;
                if (quad < 2) {
                    val = fmaf(wqk[jj], qv[quad * 8 + jj], wk[jj]);
                } else if (quad == 2 && jj == 0) {
                    val = aqv;
                } else {
                    val = 0.0f;
                }
                v[jj] = (_Float16)val;
            }
            bq[q] = v;
        }
    }

    half8 ones;
    #pragma unroll
    for (int jj = 0; jj < 8; ++jj) ones[jj] = (_Float16)1.0f;
    f32x4 Oc = {0.f, 0.f, 0.f, 0.f};
    f32x4 Dn = {0.f, 0.f, 0.f, 0.f};
    f32x4 zc = {0.f, 0.f, 0.f, 0.f};

    _Float16* Ew = El[w];

    int t_beg = ks * 1024;
    #pragma unroll 1
    for (int t0 = t_beg; t0 < t_beg + 1024; t0 += 32) {
        __syncthreads();
        {   // stage K tile (32 keys x 16 f32 -> f16), coalesced float2 reads
            int key = tid >> 3, ip = (tid & 7) * 2;
            float2 kv = *(const float2*)(K + base + (size_t)(t0 + key) * 16 + ip);
            Kl[key * KPAD + ip]     = (_Float16)kv.x;
            Kl[key * KPAD + ip + 1] = (_Float16)kv.y;
            // stage V transposed: Vt[d][key]
            #pragma unroll
            for (int it = 0; it < 2; ++it) {
                int idx = tid + it * 256;
                int vk = idx >> 4, d = idx & 15;
                Vt[d * KPAD + vk] = (_Float16)V[base + (size_t)(t0 + vk) * 16 + d];
            }
        }
        __syncthreads();

        half8 bK0 = *(const half8*)&Kl[l15 * KPAD + quad * 8];
        half8 bK1 = *(const half8*)&Kl[(16 + l15) * KPAD + quad * 8];

        #pragma unroll
        for (int q = 0; q < 16; ++q) {
            f32x4 D0 = __builtin_amdgcn_mfma_f32_16x16x32_f16(bq[q], bK0, zc, 0, 0, 0);
            f32x4 D1 = __builtin_amdgcn_mfma_f32_16x16x32_f16(bq[q], bK1, zc, 0, 0, 0);
            float s0 = 0.0f, s1 = 0.0f;
            #pragma unroll
            for (int r = 0; r < 4; ++r) {
                s0 = fmaf(w2q[r], gelu_fast(D0[r]), s0);
                s1 = fmaf(w2q[r], gelu_fast(D1[r]), s1);
            }
            s0 += __shfl_xor(s0, 16, 64);
            s0 += __shfl_xor(s0, 32, 64);
            s1 += __shfl_xor(s1, 16, 64);
            s1 += __shfl_xor(s1, 32, 64);
            float u = sel_hi ? s1 : s0;               // lanes 16..31 carry sub1
            float e = EXP2F(u);                       // base-2 softmax (log2e folded in w2q)
            if (lane < 32) Ew[q * KPAD + lane] = (_Float16)e;
        }
        // E·V numerator + E·ones denominator
        half8 aE = *(const half8*)&Ew[l15 * KPAD + quad * 8];
        half8 bV = *(const half8*)&Vt[l15 * KPAD + quad * 8];
        Oc = __builtin_amdgcn_mfma_f32_16x16x32_f16(aE, bV, Oc, 0, 0, 0);
        Dn = __builtin_amdgcn_mfma_f32_16x16x32_f16(aE, ones, Dn, 0, 0, 0);
    }

    // partials: D layout row(q)=quad*4+r, col(d)=lane&15; Dn replicated across cols
    size_t pbase = (size_t)(ks * 32 + bh) * CC;
    #pragma unroll
    for (int r = 0; r < 4; ++r) {
        int c = qbase + quad * 4 + r;
        PO[(pbase + c) * 16 + l15] = Oc[r];
        if (l15 == 0) PDn[pbase + c] = Dn[r];
    }
}

// ---------------- combine key-split partials -> AT [B,C,D] ----------------
__global__ __launch_bounds__(256) void k_attn_comb(const float* __restrict__ PO,
                                                   const float* __restrict__ PDn,
                                                   float* __restrict__ AT) {
    int idx = blockIdx.x * 256 + threadIdx.x;        // 65536 queries
    int bh = idx >> 11, cq = idx & (CC - 1);
    float4 o0 = {0,0,0,0}, o1 = {0,0,0,0}, o2 = {0,0,0,0}, o3 = {0,0,0,0};
    float dn = 0.0f;
    #pragma unroll
    for (int s = 0; s < 2; ++s) {
        const float4* p = (const float4*)(PO + ((size_t)(s * 32 + bh) * CC + cq) * 16);
        float4 a = p[0], b = p[1], c = p[2], d = p[3];
        o0.x += a.x; o0.y += a.y; o0.z += a.z; o0.w += a.w;
        o1.x += b.x; o1.y += b.y; o1.z += b.z; o1.w += b.w;
        o2.x += c.x; o2.y += c.y; o2.z += c.z; o2.w += c.w;
        o3.x += d.x; o3.y += d.y; o3.z += d.z; o3.w += d.w;
        dn += PDn[(size_t)(s * 32 + bh) * CC + cq];
    }
    float inv = 1.0f / dn;
    int b = bh >> 2, hh = bh & 3;
    float4* dst = (float4*)(AT + ((size_t)(b * CC + cq)) * DD + hh * 16);
    float4 r0 = {o0.x*inv, o0.y*inv, o0.z*inv, o0.w*inv};
    float4 r1 = {o1.x*inv, o1.y*inv, o1.z*inv, o1.w*inv};
    float4 r2 = {o2.x*inv, o2.y*inv, o2.z*inv, o2.w*inv};
    float4 r3 = {o3.x*inv, o3.y*inv, o3.z*inv, o3.w*inv};
    dst[0] = r0; dst[1] = r1; dst[2] = r2; dst[3] = r3;
}

// ---------------- fused post-attention: oproj + LN1 + FFN + LN2 (1 row/block) ----------------
__global__ __launch_bounds__(256) void k_post(const float* __restrict__ AT,
                                              const float* __restrict__ ow, const float* __restrict__ ob,
                                              const float* __restrict__ g1, const float* __restrict__ be1,
                                              const float* __restrict__ f1w, const float* __restrict__ f1b,
                                              const float* __restrict__ f2w, const float* __restrict__ f2b,
                                              const float* __restrict__ g2, const float* __restrict__ be2,
                                              float* __restrict__ h) {
    int bc = blockIdx.x;
    int t  = threadIdx.x;
    int j = t & 63, part = t >> 6;
    __shared__ __attribute__((aligned(16))) float ar[64];
    __shared__ __attribute__((aligned(16))) float hln[64];
    __shared__ __attribute__((aligned(16))) float u[256];
    __shared__ float parts[4][64];
    if (t < 64) ar[t] = AT[(size_t)bc * 64 + t];
    __syncthreads();
    // out-proj: (part,j) computes a 16-chunk partial of row j's 64-dot
    {
        float p = 0.0f;
        const float4* a4 = (const float4*)(ar + part * 16);
        const float4* w4 = (const float4*)(ow + j * 64 + part * 16);
        #pragma unroll
        for (int i = 0; i < 4; ++i) {
            float4 a = a4[i], wv = w4[i];
            p = fmaf(a.x, wv.x, fmaf(a.y, wv.y, fmaf(a.z, wv.z, fmaf(a.w, wv.w, p))));
        }
        parts[part][j] = p;
    }
    __syncthreads();
    if (t < 64) {                                    // wave 0: residual + LN1
        float o = ob[t] + parts[0][t] + parts[1][t] + parts[2][t] + parts[3][t];
        float x = h[(size_t)bc * 64 + t] + o;
        float m  = wave_sum64(x) * (1.0f / 64.0f);
        float dv = x - m;
        float vv = wave_sum64(dv * dv) * (1.0f / 64.0f);
        float r  = __builtin_amdgcn_rsqf(vv + 1e-5f);
        hln[t] = fmaf(dv * r, g1[t], be1[t]);
    }
    __syncthreads();
    // FFN layer 1: 256 hidden units
    {
        float a = f1b[t];
        const float4* hr4 = (const float4*)hln;
        const float4* w4  = (const float4*)(f1w + t * 64);
        #pragma unroll
        for (int i = 0; i < 16; ++i) {
            float4 hv = hr4[i], wv = w4[i];
            a = fmaf(hv.x, wv.x, fmaf(hv.y, wv.y, fmaf(hv.z, wv.z, fmaf(hv.w, wv.w, a))));
        }
        u[t] = gelu_f(a);
    }
    __syncthreads();
    // FFN layer 2 partials
    {
        float p = 0.0f;
        const float4* u4 = (const float4*)(u + part * 64);
        const float4* w4 = (const float4*)(f2w + j * 256 + part * 64);
        #pragma unroll
        for (int i = 0; i < 16; ++i) {
            float4 uv = u4[i], wv = w4[i];
            p = fmaf(uv.x, wv.x, fmaf(uv.y, wv.y, fmaf(uv.z, wv.z, fmaf(uv.w, wv.w, p))));
        }
        parts[part][j] = p;
    }
    __syncthreads();
    if (t < 64) {                                    // wave 0: residual + LN2
        float o = f2b[t] + parts[0][t] + parts[1][t] + parts[2][t] + parts[3][t];
        float x = hln[t] + o;
        float m  = wave_sum64(x) * (1.0f / 64.0f);
        float dv = x - m;
        float vv = wave_sum64(dv * dv) * (1.0f / 64.0f);
        float r  = __builtin_amdgcn_rsqf(vv + 1e-5f);
        h[(size_t)bc * 64 + t] = fmaf(dv * r, g2[t], be2[t]);
    }
}

// ---------------- task-query readout ----------------
__global__ __launch_bounds__(256) void k_readout(const float* __restrict__ h,
                                                 const float* __restrict__ tq,
                                                 const float* __restrict__ hw, const float* __restrict__ hb,
                                                 float* __restrict__ out) {
    int b = blockIdx.x;
    int t = threadIdx.x;
    __shared__ float ebuf[2048];
    __shared__ float tqs[64];
    __shared__ float sred[256];
    __shared__ float red[4][64];
    if (t < 64) tqs[t] = tq[t];
    __syncthreads();
    float ss = 0.0f;
    for (int c = t; c < CC; c += 256) {
        const float* hrow = h + ((size_t)b * CC + c) * 64;
        float s = 0.0f;
        #pragma unroll
        for (int d = 0; d < 64; ++d) s = fmaf(hrow[d], tqs[d], s);
        float e = __expf(s * 0.125f);                 // scores ~ +-0.1: max-free safe
        ebuf[c] = e; ss += e;
    }
    sred[t] = ss;
    __syncthreads();
    for (int o = 128; o; o >>= 1) {
        if (t < o) sred[t] += sred[t + o];
        __syncthreads();
    }
    float inv = 1.0f / sred[0];
    int d = t & 63, ch = t >> 6;
    float p = 0.0f;
    for (int c = ch * 512; c < ch * 512 + 512; ++c)
        p = fmaf(ebuf[c], h[((size_t)b * CC + c) * 64 + d], p);
    red[ch][d] = p;
    __syncthreads();
    if (t < 64) red[0][t] = (red[0][t] + red[1][t] + red[2][t] + red[3][t]) * inv;
    __syncthreads();
    if (t < 10) {
        float o = hb[t];
        #pragma unroll
        for (int d2 = 0; d2 < 64; ++d2) o = fmaf(red[0][d2], hw[t * 64 + d2], o);
        out[b * 10 + t] = o;
    }
}

extern "C" void kernel_launch(void* const* d_in, const int* in_sizes, int n_in,
                              void* d_out, int out_size, void* d_ws, size_t ws_size,
                              hipStream_t stream) {
    (void)in_sizes; (void)n_in; (void)out_size; (void)ws_size;
    const float* x    = (const float*)d_in[0];
    const float* role = (const float*)d_in[1];
    const float* fw   = (const float*)d_in[2];
    const float* qw   = (const float*)d_in[3];
    const float* qb   = (const float*)d_in[4];
    const float* kw   = (const float*)d_in[5];
    const float* kb   = (const float*)d_in[6];
    const float* vw   = (const float*)d_in[7];
    const float* vb   = (const float*)d_in[8];
    const float* w1   = (const float*)d_in[9];
    const float* b1   = (const float*)d_in[10];
    const float* w2   = (const float*)d_in[11];
    // d_in[12] = b2: softmax-shift-invariant, dropped
    const float* ow   = (const float*)d_in[13];
    const float* ob   = (const float*)d_in[14];
    const float* g1   = (const float*)d_in[15];
    const float* be1  = (const float*)d_in[16];
    const float* f1w  = (const float*)d_in[17];
    const float* f1b  = (const float*)d_in[18];
    const float* f2w  = (const float*)d_in[19];
    const float* f2b  = (const float*)d_in[20];
    const float* g2   = (const float*)d_in[21];
    const float* be2  = (const float*)d_in[22];
    const float* tq   = (const float*)d_in[23];
    const float* hw   = (const float*)d_in[24];
    const float* hb   = (const float*)d_in[25];

    float* ws   = (float*)d_ws;
    const size_t M = 1048576;                        // B*C*D
    float* H    = ws;
    float* Q    = ws + 1 * M;
    float* K    = ws + 2 * M;
    float* V    = ws + 3 * M;
    float* Abuf = ws + 4 * M;
    float* AT   = ws + 5 * M;
    float* PO   = ws + 6 * M;                        // 2*32*2048*16 = 2M floats
    float* PDn  = ws + 8 * M;                        // 2*32*2048 = 128K floats

    k_binding<<<4096, 256, 0, stream>>>(x, role, fw, H);
    for (int l = 0; l < LL; ++l) {
        k_qkv<<<4096, 256, 0, stream>>>(H, qw + l * 4096, qb + l * 64, kw + l * 4096, kb + l * 64,
                                        vw + l * 4096, vb + l * 64, w1 + l * 768, b1 + l * 16,
                                        Q, K, V, Abuf);
        k_attn<<<2048, 256, 0, stream>>>(Q, K, V, Abuf, w1 + l * 768, w2 + l * 16, PO, PDn);
        k_attn_comb<<<256, 256, 0, stream>>>(PO, PDn, AT);
        k_post<<<16384, 256, 0, stream>>>(AT, ow + l * 4096, ob + l * 64, g1 + l * 64, be1 + l * 64,
                                          f1w + l * 16384, f1b + l * 256, f2w + l * 16384,
                                          f2b + l * 64, g2 + l * 64, be2 + l * 64, H);
    }
    k_readout<<<8, 256, 0, stream>>>(H, tq, hw, hb, (float*)d_out);
}

// Round 7
// 3425.214 us; speedup vs baseline: 1.0124x; 1.0124x over previous
//
#include <hip/hip_runtime.h>
#include <math.h>
#include <cmath>

// Problem constants
#define BB 8
#define CC 2048
#define DD 64
#define LL 3
#define HH 4
#define DHH 16
#define KPAD 40   // halves per LDS row: 32 keys + 8 pad (80B = 16B-aligned)
#define GCLAMP 4.25f

typedef _Float16 half8 __attribute__((ext_vector_type(8)));
typedef float f32x4 __attribute__((ext_vector_type(4)));
typedef float f32x2 __attribute__((ext_vector_type(2)));

#if defined(__has_builtin)
#if __has_builtin(__builtin_amdgcn_exp2f)
#define EXP2F(x) __builtin_amdgcn_exp2f(x)
#else
#define EXP2F(x) __expf((x) * 0.693147180559945f)
#endif
#else
#define EXP2F(x) __expf((x) * 0.693147180559945f)
#endif

// ---------------- exact GELU via A&S 7.1.26 erf (residual-path kernels) ----------------
__device__ __forceinline__ float gelu_f(float x) {
    float z  = 0.70710678118654752f * x;
    float az = fabsf(z);
    float t  = __builtin_amdgcn_rcpf(fmaf(0.3275911f, az, 1.0f));
    float p  = t * fmaf(t, fmaf(t, fmaf(t, fmaf(t, 1.061405429f, -1.453152027f),
                                        1.421413741f), -0.284496736f), 0.254829592f);
    float e  = __expf(-z * z);
    float r  = p * e;                                // erfc(|z|)
    float phi = (x >= 0.0f) ? fmaf(-0.5f, r, 1.0f) : 0.5f * r;
    return x * phi;
}

// ---------------- packed polynomial erf-GELU (score path; trans-free) ----------------
// gelu(x) = 0.5x(1 + E(t)), t = clamp(x, +-4.25), E = t*P(t^2); P fit on host vs erf.
__device__ __forceinline__ f32x2 gelu_poly2(f32x2 x, float c0, float c1, float c2,
                                            float c3, float c4, float c5, float c6) {
    f32x2 lo = {-GCLAMP, -GCLAMP}, hi = {GCLAMP, GCLAMP};
    f32x2 t = __builtin_elementwise_min(__builtin_elementwise_max(x, lo), hi);
    f32x2 u = t * t;
    f32x2 P = {c6, c6};
    f32x2 k5 = {c5, c5}; P = __builtin_elementwise_fma(P, u, k5);
    f32x2 k4 = {c4, c4}; P = __builtin_elementwise_fma(P, u, k4);
    f32x2 k3 = {c3, c3}; P = __builtin_elementwise_fma(P, u, k3);
    f32x2 k2 = {c2, c2}; P = __builtin_elementwise_fma(P, u, k2);
    f32x2 k1 = {c1, c1}; P = __builtin_elementwise_fma(P, u, k1);
    f32x2 k0 = {c0, c0}; P = __builtin_elementwise_fma(P, u, k0);
    f32x2 E = t * P;
    f32x2 halfc = {0.5f, 0.5f};
    f32x2 h = x * halfc;
    return __builtin_elementwise_fma(h, E, h);
}

__device__ __forceinline__ float wave_sum64(float v) {
    #pragma unroll
    for (int off = 32; off; off >>= 1) v += __shfl_xor(v, off, 64);
    return v;
}

// ---------------- host: least-squares fit of E(t)=erf(t/sqrt2) ~ t*P(t^2) ----------------
// Chebyshev-node sampling on u=t^2 in [0, 4.25^2]; t-weighted basis (matches the
// 0.5*x*E error metric). Deterministic every call (graph-capture safe).
static void fit_gelu_poly(float cf[7]) {
    const int NS = 512;
    const int M = 7;
    const double umax = (double)GCLAMP * (double)GCLAMP;
    double AtA[7][7], Atb[7];
    for (int i = 0; i < M; ++i) { Atb[i] = 0.0; for (int j = 0; j < M; ++j) AtA[i][j] = 0.0; }
    for (int k = 0; k <= NS; ++k) {
        double u = umax * 0.5 * (1.0 - cos(3.14159265358979323846 * (double)k / NS));
        double t = sqrt(u);
        double g = erf(t * 0.7071067811865476);
        double v = u / umax;
        double phi[7];
        double p = t;
        for (int j = 0; j < M; ++j) { phi[j] = p; p *= v; }
        for (int i = 0; i < M; ++i) {
            Atb[i] += phi[i] * g;
            for (int j = 0; j < M; ++j) AtA[i][j] += phi[i] * phi[j];
        }
    }
    for (int col = 0; col < M; ++col) {              // GE w/ partial pivoting
        int piv = col;
        for (int r = col + 1; r < M; ++r)
            if (fabs(AtA[r][col]) > fabs(AtA[piv][col])) piv = r;
        if (piv != col) {
            for (int j = 0; j < M; ++j) { double tm = AtA[col][j]; AtA[col][j] = AtA[piv][j]; AtA[piv][j] = tm; }
            double tb = Atb[col]; Atb[col] = Atb[piv]; Atb[piv] = tb;
        }
        double d = AtA[col][col];
        for (int r = col + 1; r < M; ++r) {
            double f = AtA[r][col] / d;
            for (int j = col; j < M; ++j) AtA[r][j] -= f * AtA[col][j];
            Atb[r] -= f * Atb[col];
        }
    }
    double c[7];
    for (int i = M - 1; i >= 0; --i) {
        double s = Atb[i];
        for (int j = i + 1; j < M; ++j) s -= AtA[i][j] * c[j];
        c[i] = s / AtA[i][i];
    }
    double scale = 1.0;                               // convert v-basis -> u-basis
    for (int j = 0; j < M; ++j) { cf[j] = (float)(c[j] * scale); scale /= umax; }
}

// ---------------- binding encoder ----------------
__global__ __launch_bounds__(256) void k_binding(const float* __restrict__ x,
                                                 const float* __restrict__ role,
                                                 const float* __restrict__ fw,
                                                 float* __restrict__ h) {
    int idx = blockIdx.x * 256 + threadIdx.x;        // B*C*D = 1048576
    int d  = idx & 63;
    int bc = idx >> 6;
    float xl = log1pf(fmaxf(x[bc], 0.0f));
    float f  = gelu_f(xl * fw[d]);
    h[idx] = role[(bc & (CC - 1)) * DD + d] * f;
}

// ---------------- QKV projection + Aq (=qp+b1) precompute ----------------
__global__ __launch_bounds__(256) void k_qkv(const float* __restrict__ h,
                                             const float* __restrict__ qw, const float* __restrict__ qb,
                                             const float* __restrict__ kw, const float* __restrict__ kb,
                                             const float* __restrict__ vw, const float* __restrict__ vb,
                                             const float* __restrict__ w1, const float* __restrict__ b1,
                                             float* __restrict__ Q, float* __restrict__ K,
                                             float* __restrict__ V, float* __restrict__ A) {
    __shared__ __attribute__((aligned(16))) float hrow[4][64];
    __shared__ float qrow[4][64];
    int r  = threadIdx.x >> 6;
    int j  = threadIdx.x & 63;
    int bc = blockIdx.x * 4 + r;                     // 0..16383
    hrow[r][j] = h[(size_t)bc * 64 + j];
    __syncthreads();
    float aq = qb[j], ak = kb[j], av = vb[j];
    const float4* hr4 = (const float4*)hrow[r];
    const float4* qw4 = (const float4*)(qw + j * 64);
    const float4* kw4 = (const float4*)(kw + j * 64);
    const float4* vw4 = (const float4*)(vw + j * 64);
    #pragma unroll
    for (int i = 0; i < 16; ++i) {
        float4 hv = hr4[i];
        float4 a = qw4[i], b = kw4[i], c = vw4[i];
        aq = fmaf(hv.x, a.x, fmaf(hv.y, a.y, fmaf(hv.z, a.z, fmaf(hv.w, a.w, aq))));
        ak = fmaf(hv.x, b.x, fmaf(hv.y, b.y, fmaf(hv.z, b.z, fmaf(hv.w, b.w, ak))));
        av = fmaf(hv.x, c.x, fmaf(hv.y, c.y, fmaf(hv.z, c.z, fmaf(hv.w, c.w, av))));
    }
    int head = j >> 4, dh = j & 15;
    int b = bc >> 11, c = bc & (CC - 1);
    size_t o = ((size_t)(b * HH + head) * CC + c) * DHH + dh;
    Q[o] = aq; K[o] = ak; V[o] = av;
    qrow[r][j] = aq;
    __syncthreads();
    float aA = b1[dh];
    #pragma unroll
    for (int i = 0; i < 16; ++i)
        aA = fmaf(qrow[r][head * 16 + i], w1[dh * 48 + i], aA);
    A[o] = aA;
}

// ---------------- MFMA attention with MLP scores (poly gelu, no key split) ----------------
// grid: qt(32) x bh(32) = 1024 blocks, 4 waves/block, 16 q/wave.
__global__ __launch_bounds__(256, 4) void k_attn(const float* __restrict__ Q, const float* __restrict__ K,
                                                 const float* __restrict__ V, const float* __restrict__ A,
                                                 const float* __restrict__ w1g, const float* __restrict__ w2g,
                                                 float* __restrict__ AT,
                                                 float c0, float c1, float c2, float c3,
                                                 float c4, float c5, float c6) {
    __shared__ __attribute__((aligned(16))) _Float16 Kl[32 * KPAD];   // [key][i0..15,16=1,17..=0]
    __shared__ __attribute__((aligned(16))) _Float16 Vt[16 * KPAD];   // [d][key]
    __shared__ __attribute__((aligned(16))) _Float16 El[4][16 * KPAD];// per wave [q][key]

    int tid  = threadIdx.x;
    int lane = tid & 63;
    int w    = tid >> 6;
    int quad = lane >> 4;
    int l15  = lane & 15;
    int qt = blockIdx.x & 31;
    int bh = blockIdx.x >> 5;
    size_t base = (size_t)bh * (CC * DHH);
    int qbase = qt * 64 + w * 16;

    // one-time constant region of Kl: [16]=1.0, [17..39]=0 per key row
    for (int idx = tid; idx < 32 * 24; idx += 256) {
        int row = idx / 24, off = 16 + idx % 24;
        Kl[row * KPAD + off] = (off == 16) ? (_Float16)1.0f : (_Float16)0.0f;
    }

    // per-lane w2 for rows j = quad*4+r, with 1/sqrt(16)*log2(e) folded (softmax in base 2)
    float w2q[4];
    #pragma unroll
    for (int r = 0; r < 4; ++r) w2q[r] = w2g[quad * 4 + r] * (0.25f * 1.44269504f);

    bool sel_hi = (lane & 16) != 0;                  // quads 1,3 -> sub1 value at store

    // W1k/W1qk slices are q-invariant: hoist to registers (per-lane j=l15, i=quad*8+jj)
    float wk[8], wqk[8];
    #pragma unroll
    for (int jj = 0; jj < 8; ++jj) {
        int i = (quad & 1) * 8 + jj;
        wk[jj]  = w1g[l15 * 48 + 16 + ((quad < 2) ? quad * 8 + jj : i)];
        wqk[jj] = w1g[l15 * 48 + 32 + ((quad < 2) ? quad * 8 + jj : i)];
    }

    // Bq A-frags: m=j=lane&15, kdim=i=quad*8+jj. quads0,1: W1qk[j][i]*q[i]+W1k[j][i];
    // quad2 jj=0: Aq[j]; else 0. 16 frags (32 VGPRs) live across the K loop.
    half8 bq[16];
    {
        int j = l15;
        #pragma unroll
        for (int q = 0; q < 16; ++q) {
            const float* qv = Q + base + (size_t)(qbase + q) * 16;
            float aqv = A[base + (size_t)(qbase + q) * 16 + j];
            half8 v;
            #pragma unroll
            for (int jj = 0; jj < 8; ++jj) {
                float val;
                if (quad < 2) {
                    val = fmaf(wqk[jj], qv[quad * 8 + jj], wk[jj]);
                } else if (quad == 2 && jj == 0) {
                    val = aqv;
                } else {
                    val = 0.0f;
                }
                v[jj] = (_Float16)val;
            }
            bq[q] = v;
        }
    }

    half8 ones;
    #pragma unroll
    for (int jj = 0; jj < 8; ++jj) ones[jj] = (_Float16)1.0f;
    f32x4 Oc = {0.f, 0.f, 0.f, 0.f};
    f32x4 Dn = {0.f, 0.f, 0.f, 0.f};
    f32x4 zc = {0.f, 0.f, 0.f, 0.f};

    _Float16* Ew = El[w];

    #pragma unroll 1
    for (int t0 = 0; t0 < CC; t0 += 32) {
        __syncthreads();
        {   // stage K tile (32 keys x 16 f32 -> f16), coalesced float2 reads
            int key = tid >> 3, ip = (tid & 7) * 2;
            float2 kv = *(const float2*)(K + base + (size_t)(t0 + key) * 16 + ip);
            Kl[key * KPAD + ip]     = (_Float16)kv.x;
            Kl[key * KPAD + ip + 1] = (_Float16)kv.y;
            // stage V transposed: Vt[d][key]
            #pragma unroll
            for (int it = 0; it < 2; ++it) {
                int idx = tid + it * 256;
                int vk = idx >> 4, d = idx & 15;
                Vt[d * KPAD + vk] = (_Float16)V[base + (size_t)(t0 + vk) * 16 + d];
            }
        }
        __syncthreads();

        half8 bK0 = *(const half8*)&Kl[l15 * KPAD + quad * 8];
        half8 bK1 = *(const half8*)&Kl[(16 + l15) * KPAD + quad * 8];

        #pragma unroll
        for (int q = 0; q < 16; ++q) {
            f32x4 D0 = __builtin_amdgcn_mfma_f32_16x16x32_f16(bq[q], bK0, zc, 0, 0, 0);
            f32x4 D1 = __builtin_amdgcn_mfma_f32_16x16x32_f16(bq[q], bK1, zc, 0, 0, 0);
            f32x2 s = {0.0f, 0.0f};
            #pragma unroll
            for (int r = 0; r < 4; ++r) {
                f32x2 d2 = {D0[r], D1[r]};
                f32x2 g2 = gelu_poly2(d2, c0, c1, c2, c3, c4, c5, c6);
                f32x2 wv = {w2q[r], w2q[r]};
                s = __builtin_elementwise_fma(wv, g2, s);
            }
            float s0 = s[0], s1 = s[1];
            s0 += __shfl_xor(s0, 16, 64);
            s0 += __shfl_xor(s0, 32, 64);
            s1 += __shfl_xor(s1, 16, 64);
            s1 += __shfl_xor(s1, 32, 64);
            float uu = sel_hi ? s1 : s0;              // lanes 16..31 carry sub1
            float e = EXP2F(uu);                      // base-2 softmax (log2e folded in w2q)
            if (lane < 32) Ew[q * KPAD + lane] = (_Float16)e;
        }
        // E·V numerator + E·ones denominator
        half8 aE = *(const half8*)&Ew[l15 * KPAD + quad * 8];
        half8 bV = *(const half8*)&Vt[l15 * KPAD + quad * 8];
        Oc = __builtin_amdgcn_mfma_f32_16x16x32_f16(aE, bV, Oc, 0, 0, 0);
        Dn = __builtin_amdgcn_mfma_f32_16x16x32_f16(aE, ones, Dn, 0, 0, 0);
    }

    // D layout: row(q)=quad*4+r, col(d)=lane&15; Dn replicated across cols
    int b = bh >> 2, hh = bh & 3;
    #pragma unroll
    for (int r = 0; r < 4; ++r) {
        int c = qbase + quad * 4 + r;
        AT[((size_t)(b * CC + c)) * DD + hh * 16 + l15] = Oc[r] / Dn[r];
    }
}

// ---------------- fused post-attention: oproj + LN1 + FFN + LN2 (1 row/block) ----------------
__global__ __launch_bounds__(256) void k_post(const float* __restrict__ AT,
                                              const float* __restrict__ ow, const float* __restrict__ ob,
                                              const float* __restrict__ g1, const float* __restrict__ be1,
                                              const float* __restrict__ f1w, const float* __restrict__ f1b,
                                              const float* __restrict__ f2w, const float* __restrict__ f2b,
                                              const float* __restrict__ g2, const float* __restrict__ be2,
                                              float* __restrict__ h) {
    int bc = blockIdx.x;
    int t  = threadIdx.x;
    int j = t & 63, part = t >> 6;
    __shared__ __attribute__((aligned(16))) float ar[64];
    __shared__ __attribute__((aligned(16))) float hln[64];
    __shared__ __attribute__((aligned(16))) float u[256];
    __shared__ float parts[4][64];
    if (t < 64) ar[t] = AT[(size_t)bc * 64 + t];
    __syncthreads();
    {
        float p = 0.0f;
        const float4* a4 = (const float4*)(ar + part * 16);
        const float4* w4 = (const float4*)(ow + j * 64 + part * 16);
        #pragma unroll
        for (int i = 0; i < 4; ++i) {
            float4 a = a4[i], wv = w4[i];
            p = fmaf(a.x, wv.x, fmaf(a.y, wv.y, fmaf(a.z, wv.z, fmaf(a.w, wv.w, p))));
        }
        parts[part][j] = p;
    }
    __syncthreads();
    if (t < 64) {                                    // wave 0: residual + LN1
        float o = ob[t] + parts[0][t] + parts[1][t] + parts[2][t] + parts[3][t];
        float x = h[(size_t)bc * 64 + t] + o;
        float m  = wave_sum64(x) * (1.0f / 64.0f);
        float dv = x - m;
        float vv = wave_sum64(dv * dv) * (1.0f / 64.0f);
        float r  = __builtin_amdgcn_rsqf(vv + 1e-5f);
        hln[t] = fmaf(dv * r, g1[t], be1[t]);
    }
    __syncthreads();
    {
        float a = f1b[t];
        const float4* hr4 = (const float4*)hln;
        const float4* w4  = (const float4*)(f1w + t * 64);
        #pragma unroll
        for (int i = 0; i < 16; ++i) {
            float4 hv = hr4[i], wv = w4[i];
            a = fmaf(hv.x, wv.x, fmaf(hv.y, wv.y, fmaf(hv.z, wv.z, fmaf(hv.w, wv.w, a))));
        }
        u[t] = gelu_f(a);
    }
    __syncthreads();
    {
        float p = 0.0f;
        const float4* u4 = (const float4*)(u + part * 64);
        const float4* w4 = (const float4*)(f2w + j * 256 + part * 64);
        #pragma unroll
        for (int i = 0; i < 16; ++i) {
            float4 uv = u4[i], wv = w4[i];
            p = fmaf(uv.x, wv.x, fmaf(uv.y, wv.y, fmaf(uv.z, wv.z, fmaf(uv.w, wv.w, p))));
        }
        parts[part][j] = p;
    }
    __syncthreads();
    if (t < 64) {                                    // wave 0: residual + LN2
        float o = f2b[t] + parts[0][t] + parts[1][t] + parts[2][t] + parts[3][t];
        float x = hln[t] + o;
        float m  = wave_sum64(x) * (1.0f / 64.0f);
        float dv = x - m;
        float vv = wave_sum64(dv * dv) * (1.0f / 64.0f);
        float r  = __builtin_amdgcn_rsqf(vv + 1e-5f);
        h[(size_t)bc * 64 + t] = fmaf(dv * r, g2[t], be2[t]);
    }
}

// ---------------- task-query readout ----------------
__global__ __launch_bounds__(256) void k_readout(const float* __restrict__ h,
                                                 const float* __restrict__ tq,
                                                 const float* __restrict__ hw, const float* __restrict__ hb,
                                                 float* __restrict__ out) {
    int b = blockIdx.x;
    int t = threadIdx.x;
    __shared__ float ebuf[2048];
    __shared__ float tqs[64];
    __shared__ float sred[256];
    __shared__ float red[4][64];
    if (t < 64) tqs[t] = tq[t];
    __syncthreads();
    float ss = 0.0f;
    for (int c = t; c < CC; c += 256) {
        const float* hrow = h + ((size_t)b * CC + c) * 64;
        float s = 0.0f;
        #pragma unroll
        for (int d = 0; d < 64; ++d) s = fmaf(hrow[d], tqs[d], s);
        float e = __expf(s * 0.125f);                 // scores ~ +-0.1: max-free safe
        ebuf[c] = e; ss += e;
    }
    sred[t] = ss;
    __syncthreads();
    for (int o = 128; o; o >>= 1) {
        if (t < o) sred[t] += sred[t + o];
        __syncthreads();
    }
    float inv = 1.0f / sred[0];
    int d = t & 63, ch = t >> 6;
    float p = 0.0f;
    for (int c = ch * 512; c < ch * 512 + 512; ++c)
        p = fmaf(ebuf[c], h[((size_t)b * CC + c) * 64 + d], p);
    red[ch][d] = p;
    __syncthreads();
    if (t < 64) red[0][t] = (red[0][t] + red[1][t] + red[2][t] + red[3][t]) * inv;
    __syncthreads();
    if (t < 10) {
        float o = hb[t];
        #pragma unroll
        for (int d2 = 0; d2 < 64; ++d2) o = fmaf(red[0][d2], hw[t * 64 + d2], o);
        out[b * 10 + t] = o;
    }
}

extern "C" void kernel_launch(void* const* d_in, const int* in_sizes, int n_in,
                              void* d_out, int out_size, void* d_ws, size_t ws_size,
                              hipStream_t stream) {
    (void)in_sizes; (void)n_in; (void)out_size; (void)ws_size;
    const float* x    = (const float*)d_in[0];
    const float* role = (const float*)d_in[1];
    const float* fw   = (const float*)d_in[2];
    const float* qw   = (const float*)d_in[3];
    const float* qb   = (const float*)d_in[4];
    const float* kw   = (const float*)d_in[5];
    const float* kb   = (const float*)d_in[6];
    const float* vw   = (const float*)d_in[7];
    const float* vb   = (const float*)d_in[8];
    const float* w1   = (const float*)d_in[9];
    const float* b1   = (const float*)d_in[10];
    const float* w2   = (const float*)d_in[11];
    // d_in[12] = b2: softmax-shift-invariant, dropped
    const float* ow   = (const float*)d_in[13];
    const float* ob   = (const float*)d_in[14];
    const float* g1   = (const float*)d_in[15];
    const float* be1  = (const float*)d_in[16];
    const float* f1w  = (const float*)d_in[17];
    const float* f1b  = (const float*)d_in[18];
    const float* f2w  = (const float*)d_in[19];
    const float* f2b  = (const float*)d_in[20];
    const float* g2   = (const float*)d_in[21];
    const float* be2  = (const float*)d_in[22];
    const float* tq   = (const float*)d_in[23];
    const float* hw   = (const float*)d_in[24];
    const float* hb   = (const float*)d_in[25];

    float cf[7];
    fit_gelu_poly(cf);                               // deterministic per call (~us, host-only)

    float* ws   = (float*)d_ws;
    const size_t M = 1048576;                        // B*C*D
    float* H    = ws;
    float* Q    = ws + 1 * M;
    float* K    = ws + 2 * M;
    float* V    = ws + 3 * M;
    float* Abuf = ws + 4 * M;
    float* AT   = ws + 5 * M;

    k_binding<<<4096, 256, 0, stream>>>(x, role, fw, H);
    for (int l = 0; l < LL; ++l) {
        k_qkv<<<4096, 256, 0, stream>>>(H, qw + l * 4096, qb + l * 64, kw + l * 4096, kb + l * 64,
                                        vw + l * 4096, vb + l * 64, w1 + l * 768, b1 + l * 16,
                                        Q, K, V, Abuf);
        k_attn<<<1024, 256, 0, stream>>>(Q, K, V, Abuf, w1 + l * 768, w2 + l * 16, AT,
                                         cf[0], cf[1], cf[2], cf[3], cf[4], cf[5], cf[6]);
        k_post<<<16384, 256, 0, stream>>>(AT, ow + l * 4096, ob + l * 64, g1 + l * 64, be1 + l * 64,
                                          f1w + l * 16384, f1b + l * 256, f2w + l * 16384,
                                          f2b + l * 64, g2 + l * 64, be2 + l * 64, H);
    }
    k_readout<<<8, 256, 0, stream>>>(H, tq, hw, hb, (float*)d_out);
}

// Round 8
// 3369.838 us; speedup vs baseline: 1.0290x; 1.0164x over previous
//
#include <hip/hip_runtime.h>
#include <math.h>
#include <cmath>

// Problem constants
#define BB 8
#define CC 2048
#define DD 64
#define LL 3
#define HH 4
#define DHH 16
#define KPAD 40   // halves per LDS row: 32 keys + 8 pad (80B = 16B-aligned)
#define GCLAMP 4.25f

typedef _Float16 half8 __attribute__((ext_vector_type(8)));
typedef float f32x4 __attribute__((ext_vector_type(4)));
typedef float f32x2 __attribute__((ext_vector_type(2)));

#if defined(__has_builtin)
#if __has_builtin(__builtin_amdgcn_exp2f)
#define EXP2F(x) __builtin_amdgcn_exp2f(x)
#else
#define EXP2F(x) __expf((x) * 0.693147180559945f)
#endif
#else
#define EXP2F(x) __expf((x) * 0.693147180559945f)
#endif

// ---------------- exact GELU via A&S 7.1.26 erf (residual-path kernels) ----------------
__device__ __forceinline__ float gelu_f(float x) {
    float z  = 0.70710678118654752f * x;
    float az = fabsf(z);
    float t  = __builtin_amdgcn_rcpf(fmaf(0.3275911f, az, 1.0f));
    float p  = t * fmaf(t, fmaf(t, fmaf(t, fmaf(t, 1.061405429f, -1.453152027f),
                                        1.421413741f), -0.284496736f), 0.254829592f);
    float e  = __expf(-z * z);
    float r  = p * e;                                // erfc(|z|)
    float phi = (x >= 0.0f) ? fmaf(-0.5f, r, 1.0f) : 0.5f * r;
    return x * phi;
}

// ---------------- packed polynomial erf-GELU (score path; trans-free) ----------------
__device__ __forceinline__ f32x2 gelu_poly2(f32x2 x, float c0, float c1, float c2,
                                            float c3, float c4, float c5, float c6) {
    f32x2 lo = {-GCLAMP, -GCLAMP}, hi = {GCLAMP, GCLAMP};
    f32x2 t = __builtin_elementwise_min(__builtin_elementwise_max(x, lo), hi);
    f32x2 u = t * t;
    f32x2 P = {c6, c6};
    f32x2 k5 = {c5, c5}; P = __builtin_elementwise_fma(P, u, k5);
    f32x2 k4 = {c4, c4}; P = __builtin_elementwise_fma(P, u, k4);
    f32x2 k3 = {c3, c3}; P = __builtin_elementwise_fma(P, u, k3);
    f32x2 k2 = {c2, c2}; P = __builtin_elementwise_fma(P, u, k2);
    f32x2 k1 = {c1, c1}; P = __builtin_elementwise_fma(P, u, k1);
    f32x2 k0 = {c0, c0}; P = __builtin_elementwise_fma(P, u, k0);
    f32x2 E = t * P;
    f32x2 halfc = {0.5f, 0.5f};
    f32x2 h = x * halfc;
    return __builtin_elementwise_fma(h, E, h);
}

__device__ __forceinline__ float wave_sum64(float v) {
    #pragma unroll
    for (int off = 32; off; off >>= 1) v += __shfl_xor(v, off, 64);
    return v;
}

// ---------------- host: least-squares fit of E(t)=erf(t/sqrt2) ~ t*P(t^2) ----------------
static void fit_gelu_poly(float cf[7]) {
    const int NS = 512;
    const int M = 7;
    const double umax = (double)GCLAMP * (double)GCLAMP;
    double AtA[7][7], Atb[7];
    for (int i = 0; i < M; ++i) { Atb[i] = 0.0; for (int j = 0; j < M; ++j) AtA[i][j] = 0.0; }
    for (int k = 0; k <= NS; ++k) {
        double u = umax * 0.5 * (1.0 - cos(3.14159265358979323846 * (double)k / NS));
        double t = sqrt(u);
        double g = erf(t * 0.7071067811865476);
        double v = u / umax;
        double phi[7];
        double p = t;
        for (int j = 0; j < M; ++j) { phi[j] = p; p *= v; }
        for (int i = 0; i < M; ++i) {
            Atb[i] += phi[i] * g;
            for (int j = 0; j < M; ++j) AtA[i][j] += phi[i] * phi[j];
        }
    }
    for (int col = 0; col < M; ++col) {              // GE w/ partial pivoting
        int piv = col;
        for (int r = col + 1; r < M; ++r)
            if (fabs(AtA[r][col]) > fabs(AtA[piv][col])) piv = r;
        if (piv != col) {
            for (int j = 0; j < M; ++j) { double tm = AtA[col][j]; AtA[col][j] = AtA[piv][j]; AtA[piv][j] = tm; }
            double tb = Atb[col]; Atb[col] = Atb[piv]; Atb[piv] = tb;
        }
        double d = AtA[col][col];
        for (int r = col + 1; r < M; ++r) {
            double f = AtA[r][col] / d;
            for (int j = col; j < M; ++j) AtA[r][j] -= f * AtA[col][j];
            Atb[r] -= f * Atb[col];
        }
    }
    double c[7];
    for (int i = M - 1; i >= 0; --i) {
        double s = Atb[i];
        for (int j = i + 1; j < M; ++j) s -= AtA[i][j] * c[j];
        c[i] = s / AtA[i][i];
    }
    double scale = 1.0;                               // convert v-basis -> u-basis
    for (int j = 0; j < M; ++j) { cf[j] = (float)(c[j] * scale); scale /= umax; }
}

// ---------------- binding encoder ----------------
__global__ __launch_bounds__(256) void k_binding(const float* __restrict__ x,
                                                 const float* __restrict__ role,
                                                 const float* __restrict__ fw,
                                                 float* __restrict__ h) {
    int idx = blockIdx.x * 256 + threadIdx.x;        // B*C*D = 1048576
    int d  = idx & 63;
    int bc = idx >> 6;
    float xl = log1pf(fmaxf(x[bc], 0.0f));
    float f  = gelu_f(xl * fw[d]);
    h[idx] = role[(bc & (CC - 1)) * DD + d] * f;
}

// ---------------- QKV projection + Aq (=qp+b1) precompute ----------------
__global__ __launch_bounds__(256) void k_qkv(const float* __restrict__ h,
                                             const float* __restrict__ qw, const float* __restrict__ qb,
                                             const float* __restrict__ kw, const float* __restrict__ kb,
                                             const float* __restrict__ vw, const float* __restrict__ vb,
                                             const float* __restrict__ w1, const float* __restrict__ b1,
                                             float* __restrict__ Q, float* __restrict__ K,
                                             float* __restrict__ V, float* __restrict__ A) {
    __shared__ __attribute__((aligned(16))) float hrow[4][64];
    __shared__ float qrow[4][64];
    int r  = threadIdx.x >> 6;
    int j  = threadIdx.x & 63;
    int bc = blockIdx.x * 4 + r;                     // 0..16383
    hrow[r][j] = h[(size_t)bc * 64 + j];
    __syncthreads();
    float aq = qb[j], ak = kb[j], av = vb[j];
    const float4* hr4 = (const float4*)hrow[r];
    const float4* qw4 = (const float4*)(qw + j * 64);
    const float4* kw4 = (const float4*)(kw + j * 64);
    const float4* vw4 = (const float4*)(vw + j * 64);
    #pragma unroll
    for (int i = 0; i < 16; ++i) {
        float4 hv = hr4[i];
        float4 a = qw4[i], b = kw4[i], c = vw4[i];
        aq = fmaf(hv.x, a.x, fmaf(hv.y, a.y, fmaf(hv.z, a.z, fmaf(hv.w, a.w, aq))));
        ak = fmaf(hv.x, b.x, fmaf(hv.y, b.y, fmaf(hv.z, b.z, fmaf(hv.w, b.w, ak))));
        av = fmaf(hv.x, c.x, fmaf(hv.y, c.y, fmaf(hv.z, c.z, fmaf(hv.w, c.w, av))));
    }
    int head = j >> 4, dh = j & 15;
    int b = bc >> 11, c = bc & (CC - 1);
    size_t o = ((size_t)(b * HH + head) * CC + c) * DHH + dh;
    Q[o] = aq; K[o] = ak; V[o] = av;
    qrow[r][j] = aq;
    __syncthreads();
    float aA = b1[dh];
    #pragma unroll
    for (int i = 0; i < 16; ++i)
        aA = fmaf(qrow[r][head * 16 + i], w1[dh * 48 + i], aA);
    A[o] = aA;
}

// ---------------- MFMA attention with MLP scores (poly gelu + staged prefetch) ----------------
// grid: qt(32) x bh(32) = 1024 blocks, 4 waves/block, 16 q/wave.
// K/V for tile t+1 are prefetched into REGISTERS during tile t's compute; the
// global-load latency that round 7 exposed between the two barriers now overlaps
// the whole compute phase (classic reg double-buffer, no extra LDS).
__global__ __launch_bounds__(256, 4) void k_attn(const float* __restrict__ Q, const float* __restrict__ K,
                                                 const float* __restrict__ V, const float* __restrict__ A,
                                                 const float* __restrict__ w1g, const float* __restrict__ w2g,
                                                 float* __restrict__ AT,
                                                 float c0, float c1, float c2, float c3,
                                                 float c4, float c5, float c6) {
    __shared__ __attribute__((aligned(16))) _Float16 Kl[32 * KPAD];   // [key][i0..15,16=1,17..=0]
    __shared__ __attribute__((aligned(16))) _Float16 Vt[16 * KPAD];   // [d][key]
    __shared__ __attribute__((aligned(16))) _Float16 El[4][16 * KPAD];// per wave [q][key]

    int tid  = threadIdx.x;
    int lane = tid & 63;
    int w    = tid >> 6;
    int quad = lane >> 4;
    int l15  = lane & 15;
    int qt = blockIdx.x & 31;
    int bh = blockIdx.x >> 5;
    size_t base = (size_t)bh * (CC * DHH);
    int qbase = qt * 64 + w * 16;

    // one-time constant region of Kl: [16]=1.0, [17..39]=0 per key row
    for (int idx = tid; idx < 32 * 24; idx += 256) {
        int row = idx / 24, off = 16 + idx % 24;
        Kl[row * KPAD + off] = (off == 16) ? (_Float16)1.0f : (_Float16)0.0f;
    }

    // per-lane w2 for rows j = quad*4+r, with 1/sqrt(16)*log2(e) folded (softmax in base 2)
    float w2q[4];
    #pragma unroll
    for (int r = 0; r < 4; ++r) w2q[r] = w2g[quad * 4 + r] * (0.25f * 1.44269504f);

    bool sel_hi = (lane & 16) != 0;                  // quads 1,3 -> sub1 value at store

    // W1k/W1qk slices are q-invariant: hoist to registers (per-lane j=l15, i=quad*8+jj)
    float wk[8], wqk[8];
    #pragma unroll
    for (int jj = 0; jj < 8; ++jj) {
        int i = (quad & 1) * 8 + jj;
        wk[jj]  = w1g[l15 * 48 + 16 + ((quad < 2) ? quad * 8 + jj : i)];
        wqk[jj] = w1g[l15 * 48 + 32 + ((quad < 2) ? quad * 8 + jj : i)];
    }

    // Bq A-frags: m=j=lane&15, kdim=i=quad*8+jj. quads0,1: W1qk[j][i]*q[i]+W1k[j][i];
    // quad2 jj=0: Aq[j]; else 0.
    half8 bq[16];
    {
        int j = l15;
        #pragma unroll
        for (int q = 0; q < 16; ++q) {
            const float* qv = Q + base + (size_t)(qbase + q) * 16;
            float aqv = A[base + (size_t)(qbase + q) * 16 + j];
            half8 v;
            #pragma unroll
            for (int jj = 0; jj < 8; ++jj) {
                float val;
                if (quad < 2) {
                    val = fmaf(wqk[jj], qv[quad * 8 + jj], wk[jj]);
                } else if (quad == 2 && jj == 0) {
                    val = aqv;
                } else {
                    val = 0.0f;
                }
                v[jj] = (_Float16)val;
            }
            bq[q] = v;
        }
    }

    half8 ones;
    #pragma unroll
    for (int jj = 0; jj < 8; ++jj) ones[jj] = (_Float16)1.0f;
    f32x4 Oc = {0.f, 0.f, 0.f, 0.f};
    f32x4 Dn = {0.f, 0.f, 0.f, 0.f};
    f32x4 zc = {0.f, 0.f, 0.f, 0.f};

    _Float16* Ew = El[w];

    // staging index map (fixed per thread)
    int skey = tid >> 3, sip = (tid & 7) * 2;        // K: thread -> (key, elem-pair)
    int vk0 = tid >> 4,          vd0 = tid & 15;     // V elem 0
    int vk1 = (tid + 256) >> 4,  vd1 = tid & 15;     // V elem 1

    // prefetch tile 0 into registers
    float2 kreg = *(const float2*)(K + base + (size_t)skey * 16 + sip);
    float  vreg0 = V[base + (size_t)vk0 * 16 + vd0];
    float  vreg1 = V[base + (size_t)vk1 * 16 + vd1];

    #pragma unroll 1
    for (int t0 = 0; t0 < CC; t0 += 32) {
        __syncthreads();                              // prior tile's LDS readers done
        Kl[skey * KPAD + sip]     = (_Float16)kreg.x;
        Kl[skey * KPAD + sip + 1] = (_Float16)kreg.y;
        Vt[vd0 * KPAD + vk0] = (_Float16)vreg0;
        Vt[vd1 * KPAD + vk1] = (_Float16)vreg1;
        {   // issue next tile's loads now; they fly during the compute below
            int tn = (t0 + 32 < CC) ? (t0 + 32) : 0;
            kreg  = *(const float2*)(K + base + (size_t)(tn + skey) * 16 + sip);
            vreg0 = V[base + (size_t)(tn + vk0) * 16 + vd0];
            vreg1 = V[base + (size_t)(tn + vk1) * 16 + vd1];
        }
        __syncthreads();                              // staging visible to all waves

        half8 bK0 = *(const half8*)&Kl[l15 * KPAD + quad * 8];
        half8 bK1 = *(const half8*)&Kl[(16 + l15) * KPAD + quad * 8];

        #pragma unroll
        for (int q = 0; q < 16; ++q) {
            f32x4 D0 = __builtin_amdgcn_mfma_f32_16x16x32_f16(bq[q], bK0, zc, 0, 0, 0);
            f32x4 D1 = __builtin_amdgcn_mfma_f32_16x16x32_f16(bq[q], bK1, zc, 0, 0, 0);
            f32x2 s = {0.0f, 0.0f};
            #pragma unroll
            for (int r = 0; r < 4; ++r) {
                f32x2 d2 = {D0[r], D1[r]};
                f32x2 g2 = gelu_poly2(d2, c0, c1, c2, c3, c4, c5, c6);
                f32x2 wv = {w2q[r], w2q[r]};
                s = __builtin_elementwise_fma(wv, g2, s);
            }
            float s0 = s[0], s1 = s[1];
            s0 += __shfl_xor(s0, 16, 64);
            s0 += __shfl_xor(s0, 32, 64);
            s1 += __shfl_xor(s1, 16, 64);
            s1 += __shfl_xor(s1, 32, 64);
            float uu = sel_hi ? s1 : s0;              // lanes 16..31 carry sub1
            float e = EXP2F(uu);                      // base-2 softmax (log2e folded in w2q)
            if (lane < 32) Ew[q * KPAD + lane] = (_Float16)e;
        }
        // E·V numerator + E·ones denominator
        half8 aE = *(const half8*)&Ew[l15 * KPAD + quad * 8];
        half8 bV = *(const half8*)&Vt[l15 * KPAD + quad * 8];
        Oc = __builtin_amdgcn_mfma_f32_16x16x32_f16(aE, bV, Oc, 0, 0, 0);
        Dn = __builtin_amdgcn_mfma_f32_16x16x32_f16(aE, ones, Dn, 0, 0, 0);
    }

    // D layout: row(q)=quad*4+r, col(d)=lane&15; Dn replicated across cols
    int b = bh >> 2, hh = bh & 3;
    #pragma unroll
    for (int r = 0; r < 4; ++r) {
        int c = qbase + quad * 4 + r;
        AT[((size_t)(b * CC + c)) * DD + hh * 16 + l15] = Oc[r] / Dn[r];
    }
}

// ---------------- fused post-attention: oproj + LN1 + FFN + LN2 (1 row/block) ----------------
__global__ __launch_bounds__(256) void k_post(const float* __restrict__ AT,
                                              const float* __restrict__ ow, const float* __restrict__ ob,
                                              const float* __restrict__ g1, const float* __restrict__ be1,
                                              const float* __restrict__ f1w, const float* __restrict__ f1b,
                                              const float* __restrict__ f2w, const float* __restrict__ f2b,
                                              const float* __restrict__ g2, const float* __restrict__ be2,
                                              float* __restrict__ h) {
    int bc = blockIdx.x;
    int t  = threadIdx.x;
    int j = t & 63, part = t >> 6;
    __shared__ __attribute__((aligned(16))) float ar[64];
    __shared__ __attribute__((aligned(16))) float hln[64];
    __shared__ __attribute__((aligned(16))) float u[256];
    __shared__ float parts[4][64];
    if (t < 64) ar[t] = AT[(size_t)bc * 64 + t];
    __syncthreads();
    {
        float p = 0.0f;
        const float4* a4 = (const float4*)(ar + part * 16);
        const float4* w4 = (const float4*)(ow + j * 64 + part * 16);
        #pragma unroll
        for (int i = 0; i < 4; ++i) {
            float4 a = a4[i], wv = w4[i];
            p = fmaf(a.x, wv.x, fmaf(a.y, wv.y, fmaf(a.z, wv.z, fmaf(a.w, wv.w, p))));
        }
        parts[part][j] = p;
    }
    __syncthreads();
    if (t < 64) {                                    // wave 0: residual + LN1
        float o = ob[t] + parts[0][t] + parts[1][t] + parts[2][t] + parts[3][t];
        float x = h[(size_t)bc * 64 + t] + o;
        float m  = wave_sum64(x) * (1.0f / 64.0f);
        float dv = x - m;
        float vv = wave_sum64(dv * dv) * (1.0f / 64.0f);
        float r  = __builtin_amdgcn_rsqf(vv + 1e-5f);
        hln[t] = fmaf(dv * r, g1[t], be1[t]);
    }
    __syncthreads();
    {
        float a = f1b[t];
        const float4* hr4 = (const float4*)hln;
        const float4* w4  = (const float4*)(f1w + t * 64);
        #pragma unroll
        for (int i = 0; i < 16; ++i) {
            float4 hv = hr4[i], wv = w4[i];
            a = fmaf(hv.x, wv.x, fmaf(hv.y, wv.y, fmaf(hv.z, wv.z, fmaf(hv.w, wv.w, a))));
        }
        u[t] = gelu_f(a);
    }
    __syncthreads();
    {
        float p = 0.0f;
        const float4* u4 = (const float4*)(u + part * 64);
        const float4* w4 = (const float4*)(f2w + j * 256 + part * 64);
        #pragma unroll
        for (int i = 0; i < 16; ++i) {
            float4 uv = u4[i], wv = w4[i];
            p = fmaf(uv.x, wv.x, fmaf(uv.y, wv.y, fmaf(uv.z, wv.z, fmaf(uv.w, wv.w, p))));
        }
        parts[part][j] = p;
    }
    __syncthreads();
    if (t < 64) {                                    // wave 0: residual + LN2
        float o = f2b[t] + parts[0][t] + parts[1][t] + parts[2][t] + parts[3][t];
        float x = hln[t] + o;
        float m  = wave_sum64(x) * (1.0f / 64.0f);
        float dv = x - m;
        float vv = wave_sum64(dv * dv) * (1.0f / 64.0f);
        float r  = __builtin_amdgcn_rsqf(vv + 1e-5f);
        h[(size_t)bc * 64 + t] = fmaf(dv * r, g2[t], be2[t]);
    }
}

// ---------------- task-query readout ----------------
__global__ __launch_bounds__(256) void k_readout(const float* __restrict__ h,
                                                 const float* __restrict__ tq,
                                                 const float* __restrict__ hw, const float* __restrict__ hb,
                                                 float* __restrict__ out) {
    int b = blockIdx.x;
    int t = threadIdx.x;
    __shared__ float ebuf[2048];
    __shared__ float tqs[64];
    __shared__ float sred[256];
    __shared__ float red[4][64];
    if (t < 64) tqs[t] = tq[t];
    __syncthreads();
    float ss = 0.0f;
    for (int c = t; c < CC; c += 256) {
        const float* hrow = h + ((size_t)b * CC + c) * 64;
        float s = 0.0f;
        #pragma unroll
        for (int d = 0; d < 64; ++d) s = fmaf(hrow[d], tqs[d], s);
        float e = __expf(s * 0.125f);                 // scores ~ +-0.1: max-free safe
        ebuf[c] = e; ss += e;
    }
    sred[t] = ss;
    __syncthreads();
    for (int o = 128; o; o >>= 1) {
        if (t < o) sred[t] += sred[t + o];
        __syncthreads();
    }
    float inv = 1.0f / sred[0];
    int d = t & 63, ch = t >> 6;
    float p = 0.0f;
    for (int c = ch * 512; c < ch * 512 + 512; ++c)
        p = fmaf(ebuf[c], h[((size_t)b * CC + c) * 64 + d], p);
    red[ch][d] = p;
    __syncthreads();
    if (t < 64) red[0][t] = (red[0][t] + red[1][t] + red[2][t] + red[3][t]) * inv;
    __syncthreads();
    if (t < 10) {
        float o = hb[t];
        #pragma unroll
        for (int d2 = 0; d2 < 64; ++d2) o = fmaf(red[0][d2], hw[t * 64 + d2], o);
        out[b * 10 + t] = o;
    }
}

extern "C" void kernel_launch(void* const* d_in, const int* in_sizes, int n_in,
                              void* d_out, int out_size, void* d_ws, size_t ws_size,
                              hipStream_t stream) {
    (void)in_sizes; (void)n_in; (void)out_size; (void)ws_size;
    const float* x    = (const float*)d_in[0];
    const float* role = (const float*)d_in[1];
    const float* fw   = (const float*)d_in[2];
    const float* qw   = (const float*)d_in[3];
    const float* qb   = (const float*)d_in[4];
    const float* kw   = (const float*)d_in[5];
    const float* kb   = (const float*)d_in[6];
    const float* vw   = (const float*)d_in[7];
    const float* vb   = (const float*)d_in[8];
    const float* w1   = (const float*)d_in[9];
    const float* b1   = (const float*)d_in[10];
    const float* w2   = (const float*)d_in[11];
    // d_in[12] = b2: softmax-shift-invariant, dropped
    const float* ow   = (const float*)d_in[13];
    const float* ob   = (const float*)d_in[14];
    const float* g1   = (const float*)d_in[15];
    const float* be1  = (const float*)d_in[16];
    const float* f1w  = (const float*)d_in[17];
    const float* f1b  = (const float*)d_in[18];
    const float* f2w  = (const float*)d_in[19];
    const float* f2b  = (const float*)d_in[20];
    const float* g2   = (const float*)d_in[21];
    const float* be2  = (const float*)d_in[22];
    const float* tq   = (const float*)d_in[23];
    const float* hw   = (const float*)d_in[24];
    const float* hb   = (const float*)d_in[25];

    float cf[7];
    fit_gelu_poly(cf);                               // deterministic per call (~us, host-only)

    float* ws   = (float*)d_ws;
    const size_t M = 1048576;                        // B*C*D
    float* H    = ws;
    float* Q    = ws + 1 * M;
    float* K    = ws + 2 * M;
    float* V    = ws + 3 * M;
    float* Abuf = ws + 4 * M;
    float* AT   = ws + 5 * M;

    k_binding<<<4096, 256, 0, stream>>>(x, role, fw, H);
    for (int l = 0; l < LL; ++l) {
        k_qkv<<<4096, 256, 0, stream>>>(H, qw + l * 4096, qb + l * 64, kw + l * 4096, kb + l * 64,
                                        vw + l * 4096, vb + l * 64, w1 + l * 768, b1 + l * 16,
                                        Q, K, V, Abuf);
        k_attn<<<1024, 256, 0, stream>>>(Q, K, V, Abuf, w1 + l * 768, w2 + l * 16, AT,
                                         cf[0], cf[1], cf[2], cf[3], cf[4], cf[5], cf[6]);
        k_post<<<16384, 256, 0, stream>>>(AT, ow + l * 4096, ob + l * 64, g1 + l * 64, be1 + l * 64,
                                          f1w + l * 16384, f1b + l * 256, f2w + l * 16384,
                                          f2b + l * 64, g2 + l * 64, be2 + l * 64, H);
    }
    k_readout<<<8, 256, 0, stream>>>(H, tq, hw, hb, (float*)d_out);
}

// Round 9
// 3284.440 us; speedup vs baseline: 1.0558x; 1.0260x over previous
//
#include <hip/hip_runtime.h>
#include <math.h>
#include <cmath>

// Problem constants
#define BB 8
#define CC 2048
#define DD 64
#define LL 3
#define HH 4
#define DHH 16
#define KPAD 40   // halves per LDS row: 32 keys + 8 pad (80B = 16B-aligned)
#define GCLAMP 4.25f

typedef _Float16 half8 __attribute__((ext_vector_type(8)));
typedef float f32x4 __attribute__((ext_vector_type(4)));
typedef float f32x2 __attribute__((ext_vector_type(2)));

#if defined(__has_builtin)
#if __has_builtin(__builtin_amdgcn_exp2f)
#define EXP2F(x) __builtin_amdgcn_exp2f(x)
#else
#define EXP2F(x) __expf((x) * 0.693147180559945f)
#endif
#else
#define EXP2F(x) __expf((x) * 0.693147180559945f)
#endif

// ---------------- exact GELU via A&S 7.1.26 erf (residual-path kernels) ----------------
__device__ __forceinline__ float gelu_f(float x) {
    float z  = 0.70710678118654752f * x;
    float az = fabsf(z);
    float t  = __builtin_amdgcn_rcpf(fmaf(0.3275911f, az, 1.0f));
    float p  = t * fmaf(t, fmaf(t, fmaf(t, fmaf(t, 1.061405429f, -1.453152027f),
                                        1.421413741f), -0.284496736f), 0.254829592f);
    float e  = __expf(-z * z);
    float r  = p * e;                                // erfc(|z|)
    float phi = (x >= 0.0f) ? fmaf(-0.5f, r, 1.0f) : 0.5f * r;
    return x * phi;
}

// ---------------- packed polynomial erf-GELU (score path; trans-free) ----------------
__device__ __forceinline__ f32x2 gelu_poly2(f32x2 x, float c0, float c1, float c2,
                                            float c3, float c4, float c5, float c6) {
    f32x2 lo = {-GCLAMP, -GCLAMP}, hi = {GCLAMP, GCLAMP};
    f32x2 t = __builtin_elementwise_min(__builtin_elementwise_max(x, lo), hi);
    f32x2 u = t * t;
    f32x2 P = {c6, c6};
    f32x2 k5 = {c5, c5}; P = __builtin_elementwise_fma(P, u, k5);
    f32x2 k4 = {c4, c4}; P = __builtin_elementwise_fma(P, u, k4);
    f32x2 k3 = {c3, c3}; P = __builtin_elementwise_fma(P, u, k3);
    f32x2 k2 = {c2, c2}; P = __builtin_elementwise_fma(P, u, k2);
    f32x2 k1 = {c1, c1}; P = __builtin_elementwise_fma(P, u, k1);
    f32x2 k0 = {c0, c0}; P = __builtin_elementwise_fma(P, u, k0);
    f32x2 E = t * P;
    f32x2 halfc = {0.5f, 0.5f};
    f32x2 h = x * halfc;
    return __builtin_elementwise_fma(h, E, h);
}

__device__ __forceinline__ float wave_sum64(float v) {
    #pragma unroll
    for (int off = 32; off; off >>= 1) v += __shfl_xor(v, off, 64);
    return v;
}

// ---------------- host: least-squares fit of E(t)=erf(t/sqrt2) ~ t*P(t^2) ----------------
static void fit_gelu_poly(float cf[7]) {
    const int NS = 512;
    const int M = 7;
    const double umax = (double)GCLAMP * (double)GCLAMP;
    double AtA[7][7], Atb[7];
    for (int i = 0; i < M; ++i) { Atb[i] = 0.0; for (int j = 0; j < M; ++j) AtA[i][j] = 0.0; }
    for (int k = 0; k <= NS; ++k) {
        double u = umax * 0.5 * (1.0 - cos(3.14159265358979323846 * (double)k / NS));
        double t = sqrt(u);
        double g = erf(t * 0.7071067811865476);
        double v = u / umax;
        double phi[7];
        double p = t;
        for (int j = 0; j < M; ++j) { phi[j] = p; p *= v; }
        for (int i = 0; i < M; ++i) {
            Atb[i] += phi[i] * g;
            for (int j = 0; j < M; ++j) AtA[i][j] += phi[i] * phi[j];
        }
    }
    for (int col = 0; col < M; ++col) {              // GE w/ partial pivoting
        int piv = col;
        for (int r = col + 1; r < M; ++r)
            if (fabs(AtA[r][col]) > fabs(AtA[piv][col])) piv = r;
        if (piv != col) {
            for (int j = 0; j < M; ++j) { double tm = AtA[col][j]; AtA[col][j] = AtA[piv][j]; AtA[piv][j] = tm; }
            double tb = Atb[col]; Atb[col] = Atb[piv]; Atb[piv] = tb;
        }
        double d = AtA[col][col];
        for (int r = col + 1; r < M; ++r) {
            double f = AtA[r][col] / d;
            for (int j = col; j < M; ++j) AtA[r][j] -= f * AtA[col][j];
            Atb[r] -= f * Atb[col];
        }
    }
    double c[7];
    for (int i = M - 1; i >= 0; --i) {
        double s = Atb[i];
        for (int j = i + 1; j < M; ++j) s -= AtA[i][j] * c[j];
        c[i] = s / AtA[i][i];
    }
    double scale = 1.0;                               // convert v-basis -> u-basis
    for (int j = 0; j < M; ++j) { cf[j] = (float)(c[j] * scale); scale /= umax; }
}

// ---------------- binding encoder ----------------
__global__ __launch_bounds__(256) void k_binding(const float* __restrict__ x,
                                                 const float* __restrict__ role,
                                                 const float* __restrict__ fw,
                                                 float* __restrict__ h) {
    int idx = blockIdx.x * 256 + threadIdx.x;        // B*C*D = 1048576
    int d  = idx & 63;
    int bc = idx >> 6;
    float xl = log1pf(fmaxf(x[bc], 0.0f));
    float f  = gelu_f(xl * fw[d]);
    h[idx] = role[(bc & (CC - 1)) * DD + d] * f;
}

// ---------------- QKV projection + Aq (=qp+b1) precompute ----------------
__global__ __launch_bounds__(256) void k_qkv(const float* __restrict__ h,
                                             const float* __restrict__ qw, const float* __restrict__ qb,
                                             const float* __restrict__ kw, const float* __restrict__ kb,
                                             const float* __restrict__ vw, const float* __restrict__ vb,
                                             const float* __restrict__ w1, const float* __restrict__ b1,
                                             float* __restrict__ Q, float* __restrict__ K,
                                             float* __restrict__ V, float* __restrict__ A) {
    __shared__ __attribute__((aligned(16))) float hrow[4][64];
    __shared__ float qrow[4][64];
    int r  = threadIdx.x >> 6;
    int j  = threadIdx.x & 63;
    int bc = blockIdx.x * 4 + r;                     // 0..16383
    hrow[r][j] = h[(size_t)bc * 64 + j];
    __syncthreads();
    float aq = qb[j], ak = kb[j], av = vb[j];
    const float4* hr4 = (const float4*)hrow[r];
    const float4* qw4 = (const float4*)(qw + j * 64);
    const float4* kw4 = (const float4*)(kw + j * 64);
    const float4* vw4 = (const float4*)(vw + j * 64);
    #pragma unroll
    for (int i = 0; i < 16; ++i) {
        float4 hv = hr4[i];
        float4 a = qw4[i], b = kw4[i], c = vw4[i];
        aq = fmaf(hv.x, a.x, fmaf(hv.y, a.y, fmaf(hv.z, a.z, fmaf(hv.w, a.w, aq))));
        ak = fmaf(hv.x, b.x, fmaf(hv.y, b.y, fmaf(hv.z, b.z, fmaf(hv.w, b.w, ak))));
        av = fmaf(hv.x, c.x, fmaf(hv.y, c.y, fmaf(hv.z, c.z, fmaf(hv.w, c.w, av))));
    }
    int head = j >> 4, dh = j & 15;
    int b = bc >> 11, c = bc & (CC - 1);
    size_t o = ((size_t)(b * HH + head) * CC + c) * DHH + dh;
    Q[o] = aq; K[o] = ak; V[o] = av;
    qrow[r][j] = aq;
    __syncthreads();
    float aA = b1[dh];
    #pragma unroll
    for (int i = 0; i < 16; ++i)
        aA = fmaf(qrow[r][head * 16 + i], w1[dh * 48 + i], aA);
    A[o] = aA;
}

// ---------------- MFMA attention with MLP scores (qt-split for occupancy) ----------------
// grid: qt(64, 32 queries each) x bh(32) = 2048 blocks = 8 blocks/CU, 4 waves/block,
// 8 q/wave. Round-8 evidence: idle is latency-chain stalls, grid-capped at 4 blocks/CU.
// Halving q/wave doubles resident waves (VGPR drops with bq[8]) -> chains interleave.
// E-buffer rows 8..15 zeroed once; EV-MFMA's unused output rows are inert.
__global__ __launch_bounds__(256, 4) void k_attn(const float* __restrict__ Q, const float* __restrict__ K,
                                                 const float* __restrict__ V, const float* __restrict__ A,
                                                 const float* __restrict__ w1g, const float* __restrict__ w2g,
                                                 float* __restrict__ AT,
                                                 float c0, float c1, float c2, float c3,
                                                 float c4, float c5, float c6) {
    __shared__ __attribute__((aligned(16))) _Float16 Kl[32 * KPAD];   // [key][i0..15,16=1,17..=0]
    __shared__ __attribute__((aligned(16))) _Float16 Vt[16 * KPAD];   // [d][key]
    __shared__ __attribute__((aligned(16))) _Float16 El[4][16 * KPAD];// per wave [q][key]

    int tid  = threadIdx.x;
    int lane = tid & 63;
    int w    = tid >> 6;
    int quad = lane >> 4;
    int l15  = lane & 15;
    int qt = blockIdx.x & 63;
    int bh = blockIdx.x >> 6;
    size_t base = (size_t)bh * (CC * DHH);
    int qbase = qt * 32 + w * 8;

    // one-time: Kl const region ([16]=1, rest 0) + zero ALL of El (rows 8..15 stay 0)
    for (int idx = tid; idx < 32 * 24; idx += 256) {
        int row = idx / 24, off = 16 + idx % 24;
        Kl[row * KPAD + off] = (off == 16) ? (_Float16)1.0f : (_Float16)0.0f;
    }
    {
        _Float16* Elf = &El[0][0];
        for (int idx = tid; idx < 4 * 16 * KPAD; idx += 256) Elf[idx] = (_Float16)0.0f;
    }

    // per-lane w2 for rows j = quad*4+r, with 1/sqrt(16)*log2(e) folded (softmax in base 2)
    float w2q[4];
    #pragma unroll
    for (int r = 0; r < 4; ++r) w2q[r] = w2g[quad * 4 + r] * (0.25f * 1.44269504f);

    bool sel_hi = (lane & 16) != 0;                  // quads 1,3 -> sub1 value at store

    // W1k/W1qk slices are q-invariant: hoist to registers (per-lane j=l15, i=quad*8+jj)
    float wk[8], wqk[8];
    #pragma unroll
    for (int jj = 0; jj < 8; ++jj) {
        int i = (quad & 1) * 8 + jj;
        wk[jj]  = w1g[l15 * 48 + 16 + ((quad < 2) ? quad * 8 + jj : i)];
        wqk[jj] = w1g[l15 * 48 + 32 + ((quad < 2) ? quad * 8 + jj : i)];
    }

    // Bq A-frags: m=j=lane&15, kdim=i=quad*8+jj. quads0,1: W1qk[j][i]*q[i]+W1k[j][i];
    // quad2 jj=0: Aq[j]; else 0. 8 frags (32 VGPRs) live across the K loop.
    half8 bq[8];
    {
        int j = l15;
        #pragma unroll
        for (int q = 0; q < 8; ++q) {
            const float* qv = Q + base + (size_t)(qbase + q) * 16;
            float aqv = A[base + (size_t)(qbase + q) * 16 + j];
            half8 v;
            #pragma unroll
            for (int jj = 0; jj < 8; ++jj) {
                float val;
                if (quad < 2) {
                    val = fmaf(wqk[jj], qv[quad * 8 + jj], wk[jj]);
                } else if (quad == 2 && jj == 0) {
                    val = aqv;
                } else {
                    val = 0.0f;
                }
                v[jj] = (_Float16)val;
            }
            bq[q] = v;
        }
    }

    half8 ones;
    #pragma unroll
    for (int jj = 0; jj < 8; ++jj) ones[jj] = (_Float16)1.0f;
    f32x4 Oc = {0.f, 0.f, 0.f, 0.f};
    f32x4 Dn = {0.f, 0.f, 0.f, 0.f};
    f32x4 zc = {0.f, 0.f, 0.f, 0.f};

    _Float16* Ew = El[w];

    // staging index map (fixed per thread)
    int skey = tid >> 3, sip = (tid & 7) * 2;        // K: thread -> (key, elem-pair)
    int vk0 = tid >> 4,          vd0 = tid & 15;     // V elem 0
    int vk1 = (tid + 256) >> 4,  vd1 = tid & 15;     // V elem 1

    // prefetch tile 0 into registers
    float2 kreg = *(const float2*)(K + base + (size_t)skey * 16 + sip);
    float  vreg0 = V[base + (size_t)vk0 * 16 + vd0];
    float  vreg1 = V[base + (size_t)vk1 * 16 + vd1];

    #pragma unroll 1
    for (int t0 = 0; t0 < CC; t0 += 32) {
        __syncthreads();                              // prior tile's LDS readers done
        Kl[skey * KPAD + sip]     = (_Float16)kreg.x;
        Kl[skey * KPAD + sip + 1] = (_Float16)kreg.y;
        Vt[vd0 * KPAD + vk0] = (_Float16)vreg0;
        Vt[vd1 * KPAD + vk1] = (_Float16)vreg1;
        {   // issue next tile's loads now; they fly during the compute below
            int tn = (t0 + 32 < CC) ? (t0 + 32) : 0;
            kreg  = *(const float2*)(K + base + (size_t)(tn + skey) * 16 + sip);
            vreg0 = V[base + (size_t)(tn + vk0) * 16 + vd0];
            vreg1 = V[base + (size_t)(tn + vk1) * 16 + vd1];
        }
        __syncthreads();                              // staging visible to all waves

        half8 bK0 = *(const half8*)&Kl[l15 * KPAD + quad * 8];
        half8 bK1 = *(const half8*)&Kl[(16 + l15) * KPAD + quad * 8];

        #pragma unroll
        for (int q = 0; q < 8; ++q) {
            f32x4 D0 = __builtin_amdgcn_mfma_f32_16x16x32_f16(bq[q], bK0, zc, 0, 0, 0);
            f32x4 D1 = __builtin_amdgcn_mfma_f32_16x16x32_f16(bq[q], bK1, zc, 0, 0, 0);
            f32x2 s = {0.0f, 0.0f};
            #pragma unroll
            for (int r = 0; r < 4; ++r) {
                f32x2 d2 = {D0[r], D1[r]};
                f32x2 g2 = gelu_poly2(d2, c0, c1, c2, c3, c4, c5, c6);
                f32x2 wv = {w2q[r], w2q[r]};
                s = __builtin_elementwise_fma(wv, g2, s);
            }
            float s0 = s[0], s1 = s[1];
            s0 += __shfl_xor(s0, 16, 64);
            s0 += __shfl_xor(s0, 32, 64);
            s1 += __shfl_xor(s1, 16, 64);
            s1 += __shfl_xor(s1, 32, 64);
            float uu = sel_hi ? s1 : s0;              // lanes 16..31 carry sub1
            float e = EXP2F(uu);                      // base-2 softmax (log2e folded in w2q)
            if (lane < 32) Ew[q * KPAD + lane] = (_Float16)e;
        }
        // E·V numerator + E·ones denominator (A rows 8..15 are zero -> inert)
        half8 aE = *(const half8*)&Ew[l15 * KPAD + quad * 8];
        half8 bV = *(const half8*)&Vt[l15 * KPAD + quad * 8];
        Oc = __builtin_amdgcn_mfma_f32_16x16x32_f16(aE, bV, Oc, 0, 0, 0);
        Dn = __builtin_amdgcn_mfma_f32_16x16x32_f16(aE, ones, Dn, 0, 0, 0);
    }

    // D layout: row(q)=quad*4+r, col(d)=lane&15; only rows 0..7 (quad<2) are real q's
    int b = bh >> 2, hh = bh & 3;
    if (quad < 2) {
        #pragma unroll
        for (int r = 0; r < 4; ++r) {
            int c = qbase + quad * 4 + r;
            AT[((size_t)(b * CC + c)) * DD + hh * 16 + l15] = Oc[r] / Dn[r];
        }
    }
}

// ---------------- fused post-attention: oproj + LN1 + FFN + LN2 (1 row/block) ----------------
__global__ __launch_bounds__(256) void k_post(const float* __restrict__ AT,
                                              const float* __restrict__ ow, const float* __restrict__ ob,
                                              const float* __restrict__ g1, const float* __restrict__ be1,
                                              const float* __restrict__ f1w, const float* __restrict__ f1b,
                                              const float* __restrict__ f2w, const float* __restrict__ f2b,
                                              const float* __restrict__ g2, const float* __restrict__ be2,
                                              float* __restrict__ h) {
    int bc = blockIdx.x;
    int t  = threadIdx.x;
    int j = t & 63, part = t >> 6;
    __shared__ __attribute__((aligned(16))) float ar[64];
    __shared__ __attribute__((aligned(16))) float hln[64];
    __shared__ __attribute__((aligned(16))) float u[256];
    __shared__ float parts[4][64];
    if (t < 64) ar[t] = AT[(size_t)bc * 64 + t];
    __syncthreads();
    {
        float p = 0.0f;
        const float4* a4 = (const float4*)(ar + part * 16);
        const float4* w4 = (const float4*)(ow + j * 64 + part * 16);
        #pragma unroll
        for (int i = 0; i < 4; ++i) {
            float4 a = a4[i], wv = w4[i];
            p = fmaf(a.x, wv.x, fmaf(a.y, wv.y, fmaf(a.z, wv.z, fmaf(a.w, wv.w, p))));
        }
        parts[part][j] = p;
    }
    __syncthreads();
    if (t < 64) {                                    // wave 0: residual + LN1
        float o = ob[t] + parts[0][t] + parts[1][t] + parts[2][t] + parts[3][t];
        float x = h[(size_t)bc * 64 + t] + o;
        float m  = wave_sum64(x) * (1.0f / 64.0f);
        float dv = x - m;
        float vv = wave_sum64(dv * dv) * (1.0f / 64.0f);
        float r  = __builtin_amdgcn_rsqf(vv + 1e-5f);
        hln[t] = fmaf(dv * r, g1[t], be1[t]);
    }
    __syncthreads();
    {
        float a = f1b[t];
        const float4* hr4 = (const float4*)hln;
        const float4* w4  = (const float4*)(f1w + t * 64);
        #pragma unroll
        for (int i = 0; i < 16; ++i) {
            float4 hv = hr4[i], wv = w4[i];
            a = fmaf(hv.x, wv.x, fmaf(hv.y, wv.y, fmaf(hv.z, wv.z, fmaf(hv.w, wv.w, a))));
        }
        u[t] = gelu_f(a);
    }
    __syncthreads();
    {
        float p = 0.0f;
        const float4* u4 = (const float4*)(u + part * 64);
        const float4* w4 = (const float4*)(f2w + j * 256 + part * 64);
        #pragma unroll
        for (int i = 0; i < 16; ++i) {
            float4 uv = u4[i], wv = w4[i];
            p = fmaf(uv.x, wv.x, fmaf(uv.y, wv.y, fmaf(uv.z, wv.z, fmaf(uv.w, wv.w, p))));
        }
        parts[part][j] = p;
    }
    __syncthreads();
    if (t < 64) {                                    // wave 0: residual + LN2
        float o = f2b[t] + parts[0][t] + parts[1][t] + parts[2][t] + parts[3][t];
        float x = hln[t] + o;
        float m  = wave_sum64(x) * (1.0f / 64.0f);
        float dv = x - m;
        float vv = wave_sum64(dv * dv) * (1.0f / 64.0f);
        float r  = __builtin_amdgcn_rsqf(vv + 1e-5f);
        h[(size_t)bc * 64 + t] = fmaf(dv * r, g2[t], be2[t]);
    }
}

// ---------------- task-query readout ----------------
__global__ __launch_bounds__(256) void k_readout(const float* __restrict__ h,
                                                 const float* __restrict__ tq,
                                                 const float* __restrict__ hw, const float* __restrict__ hb,
                                                 float* __restrict__ out) {
    int b = blockIdx.x;
    int t = threadIdx.x;
    __shared__ float ebuf[2048];
    __shared__ float tqs[64];
    __shared__ float sred[256];
    __shared__ float red[4][64];
    if (t < 64) tqs[t] = tq[t];
    __syncthreads();
    float ss = 0.0f;
    for (int c = t; c < CC; c += 256) {
        const float* hrow = h + ((size_t)b * CC + c) * 64;
        float s = 0.0f;
        #pragma unroll
        for (int d = 0; d < 64; ++d) s = fmaf(hrow[d], tqs[d], s);
        float e = __expf(s * 0.125f);                 // scores ~ +-0.1: max-free safe
        ebuf[c] = e; ss += e;
    }
    sred[t] = ss;
    __syncthreads();
    for (int o = 128; o; o >>= 1) {
        if (t < o) sred[t] += sred[t + o];
        __syncthreads();
    }
    float inv = 1.0f / sred[0];
    int d = t & 63, ch = t >> 6;
    float p = 0.0f;
    for (int c = ch * 512; c < ch * 512 + 512; ++c)
        p = fmaf(ebuf[c], h[((size_t)b * CC + c) * 64 + d], p);
    red[ch][d] = p;
    __syncthreads();
    if (t < 64) red[0][t] = (red[0][t] + red[1][t] + red[2][t] + red[3][t]) * inv;
    __syncthreads();
    if (t < 10) {
        float o = hb[t];
        #pragma unroll
        for (int d2 = 0; d2 < 64; ++d2) o = fmaf(red[0][d2], hw[t * 64 + d2], o);
        out[b * 10 + t] = o;
    }
}

extern "C" void kernel_launch(void* const* d_in, const int* in_sizes, int n_in,
                              void* d_out, int out_size, void* d_ws, size_t ws_size,
                              hipStream_t stream) {
    (void)in_sizes; (void)n_in; (void)out_size; (void)ws_size;
    const float* x    = (const float*)d_in[0];
    const float* role = (const float*)d_in[1];
    const float* fw   = (const float*)d_in[2];
    const float* qw   = (const float*)d_in[3];
    const float* qb   = (const float*)d_in[4];
    const float* kw   = (const float*)d_in[5];
    const float* kb   = (const float*)d_in[6];
    const float* vw   = (const float*)d_in[7];
    const float* vb   = (const float*)d_in[8];
    const float* w1   = (const float*)d_in[9];
    const float* b1   = (const float*)d_in[10];
    const float* w2   = (const float*)d_in[11];
    // d_in[12] = b2: softmax-shift-invariant, dropped
    const float* ow   = (const float*)d_in[13];
    const float* ob   = (const float*)d_in[14];
    const float* g1   = (const float*)d_in[15];
    const float* be1  = (const float*)d_in[16];
    const float* f1w  = (const float*)d_in[17];
    const float* f1b  = (const float*)d_in[18];
    const float* f2w  = (const float*)d_in[19];
    const float* f2b  = (const float*)d_in[20];
    const float* g2   = (const float*)d_in[21];
    const float* be2  = (const float*)d_in[22];
    const float* tq   = (const float*)d_in[23];
    const float* hw   = (const float*)d_in[24];
    const float* hb   = (const float*)d_in[25];

    float cf[7];
    fit_gelu_poly(cf);                               // deterministic per call (~us, host-only)

    float* ws   = (float*)d_ws;
    const size_t M = 1048576;                        // B*C*D
    float* H    = ws;
    float* Q    = ws + 1 * M;
    float* K    = ws + 2 * M;
    float* V    = ws + 3 * M;
    float* Abuf = ws + 4 * M;
    float* AT   = ws + 5 * M;

    k_binding<<<4096, 256, 0, stream>>>(x, role, fw, H);
    for (int l = 0; l < LL; ++l) {
        k_qkv<<<4096, 256, 0, stream>>>(H, qw + l * 4096, qb + l * 64, kw + l * 4096, kb + l * 64,
                                        vw + l * 4096, vb + l * 64, w1 + l * 768, b1 + l * 16,
                                        Q, K, V, Abuf);
        k_attn<<<2048, 256, 0, stream>>>(Q, K, V, Abuf, w1 + l * 768, w2 + l * 16, AT,
                                         cf[0], cf[1], cf[2], cf[3], cf[4], cf[5], cf[6]);
        k_post<<<16384, 256, 0, stream>>>(AT, ow + l * 4096, ob + l * 64, g1 + l * 64, be1 + l * 64,
                                          f1w + l * 16384, f1b + l * 256, f2w + l * 16384,
                                          f2b + l * 64, g2 + l * 64, be2 + l * 64, H);
    }
    k_readout<<<8, 256, 0, stream>>>(H, tq, hw, hb, (float*)d_out);
}

// Round 11
// 2746.559 us; speedup vs baseline: 1.2625x; 1.1958x over previous
//
#include <hip/hip_runtime.h>
#include <math.h>
#include <cmath>

// Problem constants
#define BB 8
#define CC 2048
#define DD 64
#define LL 3
#define HH 4
#define DHH 16
#define KPAD 40   // halves per LDS row: 32 keys + 8 pad (80B = 16B-aligned)
#define GCLAMP 4.25f

typedef _Float16 half8 __attribute__((ext_vector_type(8)));
typedef _Float16 h2    __attribute__((ext_vector_type(2)));
typedef float f32x4 __attribute__((ext_vector_type(4)));

#if defined(__has_builtin)
#if __has_builtin(__builtin_amdgcn_exp2f)
#define EXP2F(x) __builtin_amdgcn_exp2f(x)
#else
#define EXP2F(x) __expf((x) * 0.693147180559945f)
#endif
#else
#define EXP2F(x) __expf((x) * 0.693147180559945f)
#endif

// ---------------- exact GELU via A&S 7.1.26 erf (residual-path kernels) ----------------
__device__ __forceinline__ float gelu_f(float x) {
    float z  = 0.70710678118654752f * x;
    float az = fabsf(z);
    float t  = __builtin_amdgcn_rcpf(fmaf(0.3275911f, az, 1.0f));
    float p  = t * fmaf(t, fmaf(t, fmaf(t, fmaf(t, 1.061405429f, -1.453152027f),
                                        1.421413741f), -0.284496736f), 0.254829592f);
    float e  = __expf(-z * z);
    float r  = p * e;                                // erfc(|z|)
    float phi = (x >= 0.0f) ? fmaf(-0.5f, r, 1.0f) : 0.5f * r;
    return x * phi;
}

__device__ __forceinline__ float wave_sum64(float v) {
    #pragma unroll
    for (int off = 32; off; off >>= 1) v += __shfl_xor(v, off, 64);
    return v;
}

// ---------------- fp16 packed erf-GELU score pair ----------------
// For 2 hidden values x0,x1: s += w_a*gelu(x0) + w_b*gelu(x1), with w already
// carrying 0.5 (gelu = 0.5*x*(1+E)). E(t)=erf(t/sqrt2) ~ t*P(v), v=t^2/GCLAMP^2,
// Horner in half2 (v_pk_*_f16). w*x stays f32 so the linear part is exact.
__device__ __forceinline__ float score_pair(float x0, float x1, float wa, float wb, float s,
                                            h2 C0, h2 C1, h2 C2, h2 C3, h2 C4,
                                            h2 IVU, h2 LO, h2 HI) {
    h2 t = __builtin_bit_cast(h2, __builtin_amdgcn_cvt_pkrtz(x0, x1));
    t = __builtin_elementwise_min(__builtin_elementwise_max(t, LO), HI);
    h2 u = t * t;
    h2 v = u * IVU;
    h2 P = __builtin_elementwise_fma(C4, v, C3);
    P = __builtin_elementwise_fma(P, v, C2);
    P = __builtin_elementwise_fma(P, v, C1);
    P = __builtin_elementwise_fma(P, v, C0);
    h2 E = t * P;
    float m0 = wa * x0, m1 = wb * x1;
    s = s + m0;
    s = fmaf(m0, (float)E.x, s);
    s = s + m1;
    s = fmaf(m1, (float)E.y, s);
    return s;
}

// ---------------- host: deg-4 LSQ fit of erf(t/sqrt2) ~ t*P(v), v=t^2/umax ----------------
static void fit_gelu_poly(float cf[5]) {
    const int NS = 512;
    const int M = 5;
    const double umax = (double)GCLAMP * (double)GCLAMP;
    double AtA[5][5], Atb[5];
    for (int i = 0; i < M; ++i) { Atb[i] = 0.0; for (int j = 0; j < M; ++j) AtA[i][j] = 0.0; }
    for (int k = 0; k <= NS; ++k) {
        double u = umax * 0.5 * (1.0 - cos(3.14159265358979323846 * (double)k / NS));
        double t = sqrt(u);
        double g = erf(t * 0.7071067811865476);
        double v = u / umax;
        double phi[5];
        double p = t;
        for (int j = 0; j < M; ++j) { phi[j] = p; p *= v; }
        for (int i = 0; i < M; ++i) {
            Atb[i] += phi[i] * g;
            for (int j = 0; j < M; ++j) AtA[i][j] += phi[i] * phi[j];
        }
    }
    for (int col = 0; col < M; ++col) {              // GE w/ partial pivoting
        int piv = col;
        for (int r = col + 1; r < M; ++r)
            if (fabs(AtA[r][col]) > fabs(AtA[piv][col])) piv = r;
        if (piv != col) {
            for (int j = 0; j < M; ++j) { double tm = AtA[col][j]; AtA[col][j] = AtA[piv][j]; AtA[piv][j] = tm; }
            double tb = Atb[col]; Atb[col] = Atb[piv]; Atb[piv] = tb;
        }
        double d = AtA[col][col];
        for (int r = col + 1; r < M; ++r) {
            double f = AtA[r][col] / d;
            for (int j = col; j < M; ++j) AtA[r][j] -= f * AtA[col][j];
            Atb[r] -= f * Atb[col];
        }
    }
    double c[5];
    for (int i = M - 1; i >= 0; --i) {
        double s = Atb[i];
        for (int j = i + 1; j < M; ++j) s -= AtA[i][j] * c[j];
        c[i] = s / AtA[i][i];
    }
    for (int j = 0; j < M; ++j) cf[j] = (float)c[j];  // v-basis, O(0.01..0.8): fp16-safe
}

// ---------------- binding encoder ----------------
__global__ __launch_bounds__(256) void k_binding(const float* __restrict__ x,
                                                 const float* __restrict__ role,
                                                 const float* __restrict__ fw,
                                                 float* __restrict__ h) {
    int idx = blockIdx.x * 256 + threadIdx.x;        // B*C*D = 1048576
    int d  = idx & 63;
    int bc = idx >> 6;
    float xl = log1pf(fmaxf(x[bc], 0.0f));
    float f  = gelu_f(xl * fw[d]);
    h[idx] = role[(bc & (CC - 1)) * DD + d] * f;
}

// ---------------- QKV projection + Aq (=qp+b1) precompute ----------------
__global__ __launch_bounds__(256) void k_qkv(const float* __restrict__ h,
                                             const float* __restrict__ qw, const float* __restrict__ qb,
                                             const float* __restrict__ kw, const float* __restrict__ kb,
                                             const float* __restrict__ vw, const float* __restrict__ vb,
                                             const float* __restrict__ w1, const float* __restrict__ b1,
                                             float* __restrict__ Q, float* __restrict__ K,
                                             float* __restrict__ V, float* __restrict__ A) {
    __shared__ __attribute__((aligned(16))) float hrow[4][64];
    __shared__ float qrow[4][64];
    int r  = threadIdx.x >> 6;
    int j  = threadIdx.x & 63;
    int bc = blockIdx.x * 4 + r;                     // 0..16383
    hrow[r][j] = h[(size_t)bc * 64 + j];
    __syncthreads();
    float aq = qb[j], ak = kb[j], av = vb[j];
    const float4* hr4 = (const float4*)hrow[r];
    const float4* qw4 = (const float4*)(qw + j * 64);
    const float4* kw4 = (const float4*)(kw + j * 64);
    const float4* vw4 = (const float4*)(vw + j * 64);
    #pragma unroll
    for (int i = 0; i < 16; ++i) {
        float4 hv = hr4[i];
        float4 a = qw4[i], b = kw4[i], c = vw4[i];
        aq = fmaf(hv.x, a.x, fmaf(hv.y, a.y, fmaf(hv.z, a.z, fmaf(hv.w, a.w, aq))));
        ak = fmaf(hv.x, b.x, fmaf(hv.y, b.y, fmaf(hv.z, b.z, fmaf(hv.w, b.w, ak))));
        av = fmaf(hv.x, c.x, fmaf(hv.y, c.y, fmaf(hv.z, c.z, fmaf(hv.w, c.w, av))));
    }
    int head = j >> 4, dh = j & 15;
    int b = bc >> 11, c = bc & (CC - 1);
    size_t o = ((size_t)(b * HH + head) * CC + c) * DHH + dh;
    Q[o] = aq; K[o] = ak; V[o] = av;
    qrow[r][j] = aq;
    __syncthreads();
    float aA = b1[dh];
    #pragma unroll
    for (int i = 0; i < 16; ++i)
        aA = fmaf(qrow[r][head * 16 + i], w1[dh * 48 + i], aA);
    A[o] = aA;
}

// ---------------- MFMA attention with MLP scores (fp16-packed gelu core) ----------------
// grid: qt(64, 32 queries each) x bh(32) = 2048 blocks, 4 waves/block, 8 q/wave.
__global__ __launch_bounds__(256, 8) void k_attn(const float* __restrict__ Q, const float* __restrict__ K,
                                                 const float* __restrict__ V, const float* __restrict__ A,
                                                 const float* __restrict__ w1g, const float* __restrict__ w2g,
                                                 float* __restrict__ AT,
                                                 float c0, float c1, float c2, float c3, float c4) {
    __shared__ __attribute__((aligned(16))) _Float16 Kl[32 * KPAD];   // [key][i0..15,16=1,17..=0]
    __shared__ __attribute__((aligned(16))) _Float16 Vt[16 * KPAD];   // [d][key]
    __shared__ __attribute__((aligned(16))) _Float16 El[4][16 * KPAD];// per wave [q][key]

    int tid  = threadIdx.x;
    int lane = tid & 63;
    int w    = tid >> 6;
    int quad = lane >> 4;
    int l15  = lane & 15;
    int qt = blockIdx.x & 63;
    int bh = blockIdx.x >> 6;
    size_t base = (size_t)bh * (CC * DHH);
    int qbase = qt * 32 + w * 8;

    // one-time: Kl const region ([16]=1, rest 0) + zero ALL of El (rows 8..15 stay 0)
    for (int idx = tid; idx < 32 * 24; idx += 256) {
        int row = idx / 24, off = 16 + idx % 24;
        Kl[row * KPAD + off] = (off == 16) ? (_Float16)1.0f : (_Float16)0.0f;
    }
    {
        _Float16* Elf = &El[0][0];
        for (int idx = tid; idx < 4 * 16 * KPAD; idx += 256) Elf[idx] = (_Float16)0.0f;
    }

    // gelu poly constants (half2)
    h2 C0 = {(_Float16)c0, (_Float16)c0};
    h2 C1 = {(_Float16)c1, (_Float16)c1};
    h2 C2 = {(_Float16)c2, (_Float16)c2};
    h2 C3 = {(_Float16)c3, (_Float16)c3};
    h2 C4 = {(_Float16)c4, (_Float16)c4};
    const float ivu_f = 1.0f / (GCLAMP * GCLAMP);
    h2 IVU = {(_Float16)ivu_f, (_Float16)ivu_f};
    h2 LO = {(_Float16)(-GCLAMP), (_Float16)(-GCLAMP)};
    h2 HI = {(_Float16)GCLAMP, (_Float16)GCLAMP};

    // per-lane w2 for rows j = quad*4+r; fold 1/sqrt(16)*log2(e)*0.5 (gelu half)
    float w2h[4];
    #pragma unroll
    for (int r = 0; r < 4; ++r) w2h[r] = w2g[quad * 4 + r] * (0.25f * 1.44269504f * 0.5f);

    bool sel_hi = (lane & 16) != 0;                  // quads 1,3 -> sub1 value at store

    // W1k/W1qk slices are q-invariant: hoist to registers (per-lane j=l15, i=quad*8+jj)
    float wk[8], wqk[8];
    #pragma unroll
    for (int jj = 0; jj < 8; ++jj) {
        int i = (quad & 1) * 8 + jj;
        wk[jj]  = w1g[l15 * 48 + 16 + ((quad < 2) ? quad * 8 + jj : i)];
        wqk[jj] = w1g[l15 * 48 + 32 + ((quad < 2) ? quad * 8 + jj : i)];
    }

    // Bq A-frags: m=j=lane&15, kdim=i=quad*8+jj. quads0,1: W1qk[j][i]*q[i]+W1k[j][i];
    // quad2 jj=0: Aq[j]; else 0.
    half8 bq[8];
    {
        int j = l15;
        #pragma unroll
        for (int q = 0; q < 8; ++q) {
            const float* qv = Q + base + (size_t)(qbase + q) * 16;
            float aqv = A[base + (size_t)(qbase + q) * 16 + j];
            half8 v;
            #pragma unroll
            for (int jj = 0; jj < 8; ++jj) {
                float val;
                if (quad < 2) {
                    val = fmaf(wqk[jj], qv[quad * 8 + jj], wk[jj]);
                } else if (quad == 2 && jj == 0) {
                    val = aqv;
                } else {
                    val = 0.0f;
                }
                v[jj] = (_Float16)val;
            }
            bq[q] = v;
        }
    }

    half8 ones;
    #pragma unroll
    for (int jj = 0; jj < 8; ++jj) ones[jj] = (_Float16)1.0f;
    f32x4 Oc = {0.f, 0.f, 0.f, 0.f};
    f32x4 Dn = {0.f, 0.f, 0.f, 0.f};
    f32x4 zc = {0.f, 0.f, 0.f, 0.f};

    _Float16* Ew = El[w];

    // staging index map (fixed per thread)
    int skey = tid >> 3, sip = (tid & 7) * 2;        // K: thread -> (key, elem-pair)
    int vk0 = tid >> 4,          vd0 = tid & 15;     // V elem 0
    int vk1 = (tid + 256) >> 4,  vd1 = tid & 15;     // V elem 1

    // prefetch tile 0 into registers
    float2 kreg = *(const float2*)(K + base + (size_t)skey * 16 + sip);
    float  vreg0 = V[base + (size_t)vk0 * 16 + vd0];
    float  vreg1 = V[base + (size_t)vk1 * 16 + vd1];

    #pragma unroll 1
    for (int t0 = 0; t0 < CC; t0 += 32) {
        __syncthreads();                              // prior tile's LDS readers done
        Kl[skey * KPAD + sip]     = (_Float16)kreg.x;
        Kl[skey * KPAD + sip + 1] = (_Float16)kreg.y;
        Vt[vd0 * KPAD + vk0] = (_Float16)vreg0;
        Vt[vd1 * KPAD + vk1] = (_Float16)vreg1;
        {   // issue next tile's loads now; they fly during the compute below
            int tn = (t0 + 32 < CC) ? (t0 + 32) : 0;
            kreg  = *(const float2*)(K + base + (size_t)(tn + skey) * 16 + sip);
            vreg0 = V[base + (size_t)(tn + vk0) * 16 + vd0];
            vreg1 = V[base + (size_t)(tn + vk1) * 16 + vd1];
        }
        __syncthreads();                              // staging visible to all waves

        half8 bK0 = *(const half8*)&Kl[l15 * KPAD + quad * 8];
        half8 bK1 = *(const half8*)&Kl[(16 + l15) * KPAD + quad * 8];

        #pragma unroll
        for (int q = 0; q < 8; ++q) {
            f32x4 D0 = __builtin_amdgcn_mfma_f32_16x16x32_f16(bq[q], bK0, zc, 0, 0, 0);
            f32x4 D1 = __builtin_amdgcn_mfma_f32_16x16x32_f16(bq[q], bK1, zc, 0, 0, 0);
            float s0 = 0.0f, s1 = 0.0f;
            s0 = score_pair(D0[0], D0[1], w2h[0], w2h[1], s0, C0, C1, C2, C3, C4, IVU, LO, HI);
            s0 = score_pair(D0[2], D0[3], w2h[2], w2h[3], s0, C0, C1, C2, C3, C4, IVU, LO, HI);
            s1 = score_pair(D1[0], D1[1], w2h[0], w2h[1], s1, C0, C1, C2, C3, C4, IVU, LO, HI);
            s1 = score_pair(D1[2], D1[3], w2h[2], w2h[3], s1, C0, C1, C2, C3, C4, IVU, LO, HI);
            s0 += __shfl_xor(s0, 16, 64);
            s0 += __shfl_xor(s0, 32, 64);
            s1 += __shfl_xor(s1, 16, 64);
            s1 += __shfl_xor(s1, 32, 64);
            float uu = sel_hi ? s1 : s0;              // lanes 16..31 carry sub1
            float e = EXP2F(uu);                      // base-2 softmax (log2e folded in w2h)
            if (lane < 32) Ew[q * KPAD + lane] = (_Float16)e;
        }
        // E·V numerator + E·ones denominator (A rows 8..15 are zero -> inert)
        half8 aE = *(const half8*)&Ew[l15 * KPAD + quad * 8];
        half8 bV = *(const half8*)&Vt[l15 * KPAD + quad * 8];
        Oc = __builtin_amdgcn_mfma_f32_16x16x32_f16(aE, bV, Oc, 0, 0, 0);
        Dn = __builtin_amdgcn_mfma_f32_16x16x32_f16(aE, ones, Dn, 0, 0, 0);
    }

    // D layout: row(q)=quad*4+r, col(d)=lane&15; only rows 0..7 (quad<2) are real q's
    int b = bh >> 2, hh = bh & 3;
    if (quad < 2) {
        #pragma unroll
        for (int r = 0; r < 4; ++r) {
            int c = qbase + quad * 4 + r;
            AT[((size_t)(b * CC + c)) * DD + hh * 16 + l15] = Oc[r] / Dn[r];
        }
    }
}

// ---------------- fused post-attention: oproj + LN1 + FFN + LN2 (4 rows/block) ----------------
// Weights loaded once per thread and reused across 4 rows (4x less L2 traffic);
// each wave owns one row for the LN phases (no idle waves).
__global__ __launch_bounds__(256) void k_post(const float* __restrict__ AT,
                                              const float* __restrict__ ow, const float* __restrict__ ob,
                                              const float* __restrict__ g1, const float* __restrict__ be1,
                                              const float* __restrict__ f1w, const float* __restrict__ f1b,
                                              const float* __restrict__ f2w, const float* __restrict__ f2b,
                                              const float* __restrict__ g2, const float* __restrict__ be2,
                                              float* __restrict__ h) {
    int bc0 = blockIdx.x * 4;
    int t  = threadIdx.x;
    int j = t & 63, wv = t >> 6;
    __shared__ __attribute__((aligned(16))) float ar[4][64];
    __shared__ __attribute__((aligned(16))) float hln[4][64];
    __shared__ __attribute__((aligned(16))) float u[4][256];
    __shared__ float parts[4][4][64];                // [row][chunk][j]
    ar[wv][j] = AT[(size_t)(bc0 + wv) * 64 + j];
    __syncthreads();
    {   // out-proj partials: thread (wv=chunk, j=out) for all 4 rows
        float p0 = 0.f, p1 = 0.f, p2 = 0.f, p3 = 0.f;
        const float4* w4 = (const float4*)(ow + j * 64 + wv * 16);
        const float4* a0 = (const float4*)(ar[0] + wv * 16);
        const float4* a1 = (const float4*)(ar[1] + wv * 16);
        const float4* a2 = (const float4*)(ar[2] + wv * 16);
        const float4* a3 = (const float4*)(ar[3] + wv * 16);
        #pragma unroll
        for (int i = 0; i < 4; ++i) {
            float4 wvv = w4[i];
            float4 x0 = a0[i], x1 = a1[i], x2 = a2[i], x3 = a3[i];
            p0 = fmaf(x0.x, wvv.x, fmaf(x0.y, wvv.y, fmaf(x0.z, wvv.z, fmaf(x0.w, wvv.w, p0))));
            p1 = fmaf(x1.x, wvv.x, fmaf(x1.y, wvv.y, fmaf(x1.z, wvv.z, fmaf(x1.w, wvv.w, p1))));
            p2 = fmaf(x2.x, wvv.x, fmaf(x2.y, wvv.y, fmaf(x2.z, wvv.z, fmaf(x2.w, wvv.w, p2))));
            p3 = fmaf(x3.x, wvv.x, fmaf(x3.y, wvv.y, fmaf(x3.z, wvv.z, fmaf(x3.w, wvv.w, p3))));
        }
        parts[0][wv][j] = p0; parts[1][wv][j] = p1; parts[2][wv][j] = p2; parts[3][wv][j] = p3;
    }
    __syncthreads();
    {   // LN1: wave wv handles row wv
        float o = ob[j] + parts[wv][0][j] + parts[wv][1][j] + parts[wv][2][j] + parts[wv][3][j];
        float x = h[(size_t)(bc0 + wv) * 64 + j] + o;
        float m  = wave_sum64(x) * (1.0f / 64.0f);
        float dv = x - m;
        float vv = wave_sum64(dv * dv) * (1.0f / 64.0f);
        float r  = __builtin_amdgcn_rsqf(vv + 1e-5f);
        hln[wv][j] = fmaf(dv * r, g1[j], be1[j]);
    }
    __syncthreads();
    {   // FFN1: thread t computes hidden unit t for all 4 rows (weights loaded once)
        float b = f1b[t];
        float a0 = b, a1 = b, a2 = b, a3 = b;
        const float4* w4 = (const float4*)(f1w + t * 64);
        const float4* h0 = (const float4*)hln[0];
        const float4* h1 = (const float4*)hln[1];
        const float4* h2p = (const float4*)hln[2];
        const float4* h3 = (const float4*)hln[3];
        #pragma unroll
        for (int i = 0; i < 16; ++i) {
            float4 wvv = w4[i];
            float4 x0 = h0[i], x1 = h1[i], x2 = h2p[i], x3 = h3[i];
            a0 = fmaf(x0.x, wvv.x, fmaf(x0.y, wvv.y, fmaf(x0.z, wvv.z, fmaf(x0.w, wvv.w, a0))));
            a1 = fmaf(x1.x, wvv.x, fmaf(x1.y, wvv.y, fmaf(x1.z, wvv.z, fmaf(x1.w, wvv.w, a1))));
            a2 = fmaf(x2.x, wvv.x, fmaf(x2.y, wvv.y, fmaf(x2.z, wvv.z, fmaf(x2.w, wvv.w, a2))));
            a3 = fmaf(x3.x, wvv.x, fmaf(x3.y, wvv.y, fmaf(x3.z, wvv.z, fmaf(x3.w, wvv.w, a3))));
        }
        u[0][t] = gelu_f(a0); u[1][t] = gelu_f(a1); u[2][t] = gelu_f(a2); u[3][t] = gelu_f(a3);
    }
    __syncthreads();
    {   // FFN2 partials
        float p0 = 0.f, p1 = 0.f, p2 = 0.f, p3 = 0.f;
        const float4* w4 = (const float4*)(f2w + j * 256 + wv * 64);
        const float4* u0 = (const float4*)(u[0] + wv * 64);
        const float4* u1 = (const float4*)(u[1] + wv * 64);
        const float4* u2 = (const float4*)(u[2] + wv * 64);
        const float4* u3 = (const float4*)(u[3] + wv * 64);
        #pragma unroll
        for (int i = 0; i < 16; ++i) {
            float4 wvv = w4[i];
            float4 x0 = u0[i], x1 = u1[i], x2 = u2[i], x3 = u3[i];
            p0 = fmaf(x0.x, wvv.x, fmaf(x0.y, wvv.y, fmaf(x0.z, wvv.z, fmaf(x0.w, wvv.w, p0))));
            p1 = fmaf(x1.x, wvv.x, fmaf(x1.y, wvv.y, fmaf(x1.z, wvv.z, fmaf(x1.w, wvv.w, p1))));
            p2 = fmaf(x2.x, wvv.x, fmaf(x2.y, wvv.y, fmaf(x2.z, wvv.z, fmaf(x2.w, wvv.w, p2))));
            p3 = fmaf(x3.x, wvv.x, fmaf(x3.y, wvv.y, fmaf(x3.z, wvv.z, fmaf(x3.w, wvv.w, p3))));
        }
        parts[0][wv][j] = p0; parts[1][wv][j] = p1; parts[2][wv][j] = p2; parts[3][wv][j] = p3;
    }
    __syncthreads();
    {   // LN2: wave wv handles row wv
        float o = f2b[j] + parts[wv][0][j] + parts[wv][1][j] + parts[wv][2][j] + parts[wv][3][j];
        float x = hln[wv][j] + o;
        float m  = wave_sum64(x) * (1.0f / 64.0f);
        float dv = x - m;
        float vv = wave_sum64(dv * dv) * (1.0f / 64.0f);
        float r  = __builtin_amdgcn_rsqf(vv + 1e-5f);
        h[(size_t)(bc0 + wv) * 64 + j] = fmaf(dv * r, g2[j], be2[j]);
    }
}

// ---------------- task-query readout ----------------
__global__ __launch_bounds__(256) void k_readout(const float* __restrict__ h,
                                                 const float* __restrict__ tq,
                                                 const float* __restrict__ hw, const float* __restrict__ hb,
                                                 float* __restrict__ out) {
    int b = blockIdx.x;
    int t = threadIdx.x;
    __shared__ float ebuf[2048];
    __shared__ float tqs[64];
    __shared__ float sred[256];
    __shared__ float red[4][64];
    if (t < 64) tqs[t] = tq[t];
    __syncthreads();
    float ss = 0.0f;
    for (int c = t; c < CC; c += 256) {
        const float* hrow = h + ((size_t)b * CC + c) * 64;
        float s = 0.0f;
        #pragma unroll
        for (int d = 0; d < 64; ++d) s = fmaf(hrow[d], tqs[d], s);
        float e = __expf(s * 0.125f);                 // scores ~ +-0.1: max-free safe
        ebuf[c] = e; ss += e;
    }
    sred[t] = ss;
    __syncthreads();
    for (int o = 128; o; o >>= 1) {
        if (t < o) sred[t] += sred[t + o];
        __syncthreads();
    }
    float inv = 1.0f / sred[0];
    int d = t & 63, ch = t >> 6;
    float p = 0.0f;
    for (int c = ch * 512; c < ch * 512 + 512; ++c)
        p = fmaf(ebuf[c], h[((size_t)b * CC + c) * 64 + d], p);
    red[ch][d] = p;
    __syncthreads();
    if (t < 64) red[0][t] = (red[0][t] + red[1][t] + red[2][t] + red[3][t]) * inv;
    __syncthreads();
    if (t < 10) {
        float o = hb[t];
        #pragma unroll
        for (int d2 = 0; d2 < 64; ++d2) o = fmaf(red[0][d2], hw[t * 64 + d2], o);
        out[b * 10 + t] = o;
    }
}

extern "C" void kernel_launch(void* const* d_in, const int* in_sizes, int n_in,
                              void* d_out, int out_size, void* d_ws, size_t ws_size,
                              hipStream_t stream) {
    (void)in_sizes; (void)n_in; (void)out_size; (void)ws_size;
    const float* x    = (const float*)d_in[0];
    const float* role = (const float*)d_in[1];
    const float* fw   = (const float*)d_in[2];
    const float* qw   = (const float*)d_in[3];
    const float* qb   = (const float*)d_in[4];
    const float* kw   = (const float*)d_in[5];
    const float* kb   = (const float*)d_in[6];
    const float* vw   = (const float*)d_in[7];
    const float* vb   = (const float*)d_in[8];
    const float* w1   = (const float*)d_in[9];
    const float* b1   = (const float*)d_in[10];
    const float* w2   = (const float*)d_in[11];
    // d_in[12] = b2: softmax-shift-invariant, dropped
    const float* ow   = (const float*)d_in[13];
    const float* ob   = (const float*)d_in[14];
    const float* g1   = (const float*)d_in[15];
    const float* be1  = (const float*)d_in[16];
    const float* f1w  = (const float*)d_in[17];
    const float* f1b  = (const float*)d_in[18];
    const float* f2w  = (const float*)d_in[19];
    const float* f2b  = (const float*)d_in[20];
    const float* g2   = (const float*)d_in[21];
    const float* be2  = (const float*)d_in[22];
    const float* tq   = (const float*)d_in[23];
    const float* hw   = (const float*)d_in[24];
    const float* hb   = (const float*)d_in[25];

    float cf[5];
    fit_gelu_poly(cf);                               // deterministic per call (~us, host-only)

    float* ws   = (float*)d_ws;
    const size_t M = 1048576;                        // B*C*D
    float* H    = ws;
    float* Q    = ws + 1 * M;
    float* K    = ws + 2 * M;
    float* V    = ws + 3 * M;
    float* Abuf = ws + 4 * M;
    float* AT   = ws + 5 * M;

    k_binding<<<4096, 256, 0, stream>>>(x, role, fw, H);
    for (int l = 0; l < LL; ++l) {
        k_qkv<<<4096, 256, 0, stream>>>(H, qw + l * 4096, qb + l * 64, kw + l * 4096, kb + l * 64,
                                        vw + l * 4096, vb + l * 64, w1 + l * 768, b1 + l * 16,
                                        Q, K, V, Abuf);
        k_attn<<<2048, 256, 0, stream>>>(Q, K, V, Abuf, w1 + l * 768, w2 + l * 16, AT,
                                         cf[0], cf[1], cf[2], cf[3], cf[4]);
        k_post<<<4096, 256, 0, stream>>>(AT, ow + l * 4096, ob + l * 64, g1 + l * 64, be1 + l * 64,
                                         f1w + l * 16384, f1b + l * 256, f2w + l * 16384,
                                         f2b + l * 64, g2 + l * 64, be2 + l * 64, H);
    }
    k_readout<<<8, 256, 0, stream>>>(H, tq, hw, hb, (float*)d_out);
}

// Round 12
// 2604.850 us; speedup vs baseline: 1.3312x; 1.0544x over previous
//
#include <hip/hip_runtime.h>
#include <math.h>
#include <cmath>

// Problem constants
#define BB 8
#define CC 2048
#define DD 64
#define LL 3
#define HH 4
#define DHH 16
#define KPAD 40   // halves per LDS row: 32 keys + 8 pad (80B = 16B-aligned)
#define GCLAMP 4.25f

typedef _Float16 half8 __attribute__((ext_vector_type(8)));
typedef _Float16 h2    __attribute__((ext_vector_type(2)));
typedef float f32x4 __attribute__((ext_vector_type(4)));

#if defined(__has_builtin)
#if __has_builtin(__builtin_amdgcn_exp2f)
#define EXP2F(x) __builtin_amdgcn_exp2f(x)
#else
#define EXP2F(x) __expf((x) * 0.693147180559945f)
#endif
#else
#define EXP2F(x) __expf((x) * 0.693147180559945f)
#endif

// ---------------- exact GELU via A&S 7.1.26 erf (residual-path kernels) ----------------
__device__ __forceinline__ float gelu_f(float x) {
    float z  = 0.70710678118654752f * x;
    float az = fabsf(z);
    float t  = __builtin_amdgcn_rcpf(fmaf(0.3275911f, az, 1.0f));
    float p  = t * fmaf(t, fmaf(t, fmaf(t, fmaf(t, 1.061405429f, -1.453152027f),
                                        1.421413741f), -0.284496736f), 0.254829592f);
    float e  = __expf(-z * z);
    float r  = p * e;                                // erfc(|z|)
    float phi = (x >= 0.0f) ? fmaf(-0.5f, r, 1.0f) : 0.5f * r;
    return x * phi;
}

__device__ __forceinline__ float wave_sum64(float v) {
    #pragma unroll
    for (int off = 32; off; off >>= 1) v += __shfl_xor(v, off, 64);
    return v;
}

// ---------------- fp16 packed erf-GELU score pair ----------------
// For 2 hidden values x0,x1: s += w_a*gelu(x0) + w_b*gelu(x1), with w already
// carrying 0.5 (gelu = 0.5*x*(1+E)). E(t)=erf(t/sqrt2) ~ t*P(v), v=t^2/GCLAMP^2,
// Horner in half2 (v_pk_*_f16). w*x stays f32 so the linear part is exact.
__device__ __forceinline__ float score_pair(float x0, float x1, float wa, float wb, float s,
                                            h2 C0, h2 C1, h2 C2, h2 C3, h2 C4,
                                            h2 IVU, h2 LO, h2 HI) {
    h2 t = __builtin_bit_cast(h2, __builtin_amdgcn_cvt_pkrtz(x0, x1));
    t = __builtin_elementwise_min(__builtin_elementwise_max(t, LO), HI);
    h2 u = t * t;
    h2 v = u * IVU;
    h2 P = __builtin_elementwise_fma(C4, v, C3);
    P = __builtin_elementwise_fma(P, v, C2);
    P = __builtin_elementwise_fma(P, v, C1);
    P = __builtin_elementwise_fma(P, v, C0);
    h2 E = t * P;
    float m0 = wa * x0, m1 = wb * x1;
    s = s + m0;
    s = fmaf(m0, (float)E.x, s);
    s = s + m1;
    s = fmaf(m1, (float)E.y, s);
    return s;
}

// ---------------- host: deg-4 LSQ fit of erf(t/sqrt2) ~ t*P(v), v=t^2/umax ----------------
static void fit_gelu_poly(float cf[5]) {
    const int NS = 512;
    const int M = 5;
    const double umax = (double)GCLAMP * (double)GCLAMP;
    double AtA[5][5], Atb[5];
    for (int i = 0; i < M; ++i) { Atb[i] = 0.0; for (int j = 0; j < M; ++j) AtA[i][j] = 0.0; }
    for (int k = 0; k <= NS; ++k) {
        double u = umax * 0.5 * (1.0 - cos(3.14159265358979323846 * (double)k / NS));
        double t = sqrt(u);
        double g = erf(t * 0.7071067811865476);
        double v = u / umax;
        double phi[5];
        double p = t;
        for (int j = 0; j < M; ++j) { phi[j] = p; p *= v; }
        for (int i = 0; i < M; ++i) {
            Atb[i] += phi[i] * g;
            for (int j = 0; j < M; ++j) AtA[i][j] += phi[i] * phi[j];
        }
    }
    for (int col = 0; col < M; ++col) {              // GE w/ partial pivoting
        int piv = col;
        for (int r = col + 1; r < M; ++r)
            if (fabs(AtA[r][col]) > fabs(AtA[piv][col])) piv = r;
        if (piv != col) {
            for (int j = 0; j < M; ++j) { double tm = AtA[col][j]; AtA[col][j] = AtA[piv][j]; AtA[piv][j] = tm; }
            double tb = Atb[col]; Atb[col] = Atb[piv]; Atb[piv] = tb;
        }
        double d = AtA[col][col];
        for (int r = col + 1; r < M; ++r) {
            double f = AtA[r][col] / d;
            for (int j = col; j < M; ++j) AtA[r][j] -= f * AtA[col][j];
            Atb[r] -= f * Atb[col];
        }
    }
    double c[5];
    for (int i = M - 1; i >= 0; --i) {
        double s = Atb[i];
        for (int j = i + 1; j < M; ++j) s -= AtA[i][j] * c[j];
        c[i] = s / AtA[i][i];
    }
    for (int j = 0; j < M; ++j) cf[j] = (float)c[j];  // v-basis, O(0.01..0.8): fp16-safe
}

// ---------------- binding encoder ----------------
__global__ __launch_bounds__(256) void k_binding(const float* __restrict__ x,
                                                 const float* __restrict__ role,
                                                 const float* __restrict__ fw,
                                                 float* __restrict__ h) {
    int idx = blockIdx.x * 256 + threadIdx.x;        // B*C*D = 1048576
    int d  = idx & 63;
    int bc = idx >> 6;
    float xl = log1pf(fmaxf(x[bc], 0.0f));
    float f  = gelu_f(xl * fw[d]);
    h[idx] = role[(bc & (CC - 1)) * DD + d] * f;
}

// ---------------- QKV projection + Aq (=qp+b1) precompute ----------------
__global__ __launch_bounds__(256) void k_qkv(const float* __restrict__ h,
                                             const float* __restrict__ qw, const float* __restrict__ qb,
                                             const float* __restrict__ kw, const float* __restrict__ kb,
                                             const float* __restrict__ vw, const float* __restrict__ vb,
                                             const float* __restrict__ w1, const float* __restrict__ b1,
                                             float* __restrict__ Q, float* __restrict__ K,
                                             float* __restrict__ V, float* __restrict__ A) {
    __shared__ __attribute__((aligned(16))) float hrow[4][64];
    __shared__ float qrow[4][64];
    int r  = threadIdx.x >> 6;
    int j  = threadIdx.x & 63;
    int bc = blockIdx.x * 4 + r;                     // 0..16383
    hrow[r][j] = h[(size_t)bc * 64 + j];
    __syncthreads();
    float aq = qb[j], ak = kb[j], av = vb[j];
    const float4* hr4 = (const float4*)hrow[r];
    const float4* qw4 = (const float4*)(qw + j * 64);
    const float4* kw4 = (const float4*)(kw + j * 64);
    const float4* vw4 = (const float4*)(vw + j * 64);
    #pragma unroll
    for (int i = 0; i < 16; ++i) {
        float4 hv = hr4[i];
        float4 a = qw4[i], b = kw4[i], c = vw4[i];
        aq = fmaf(hv.x, a.x, fmaf(hv.y, a.y, fmaf(hv.z, a.z, fmaf(hv.w, a.w, aq))));
        ak = fmaf(hv.x, b.x, fmaf(hv.y, b.y, fmaf(hv.z, b.z, fmaf(hv.w, b.w, ak))));
        av = fmaf(hv.x, c.x, fmaf(hv.y, c.y, fmaf(hv.z, c.z, fmaf(hv.w, c.w, av))));
    }
    int head = j >> 4, dh = j & 15;
    int b = bc >> 11, c = bc & (CC - 1);
    size_t o = ((size_t)(b * HH + head) * CC + c) * DHH + dh;
    Q[o] = aq; K[o] = ak; V[o] = av;
    qrow[r][j] = aq;
    __syncthreads();
    float aA = b1[dh];
    #pragma unroll
    for (int i = 0; i < 16; ++i)
        aA = fmaf(qrow[r][head * 16 + i], w1[dh * 48 + i], aA);
    A[o] = aA;
}

// ---------------- MFMA attention with MLP scores (fp16-packed gelu core) ----------------
// grid: qt(64, 32 queries each) x bh(32) = 2048 blocks, 4 waves/block, 8 q/wave.
// __launch_bounds__(256,6): 85-VGPR cap fits the ~80-reg live set (round 11's (256,8)
// forced a 64-reg cap -> scratch spills: FETCH 1.4 GB, WRITE 133 MB). 6 waves/SIMD
// keeps the round-11 occupancy gain without the spill traffic.
__global__ __launch_bounds__(256, 6) void k_attn(const float* __restrict__ Q, const float* __restrict__ K,
                                                 const float* __restrict__ V, const float* __restrict__ A,
                                                 const float* __restrict__ w1g, const float* __restrict__ w2g,
                                                 float* __restrict__ AT,
                                                 float c0, float c1, float c2, float c3, float c4) {
    __shared__ __attribute__((aligned(16))) _Float16 Kl[32 * KPAD];   // [key][i0..15,16=1,17..=0]
    __shared__ __attribute__((aligned(16))) _Float16 Vt[16 * KPAD];   // [d][key]
    __shared__ __attribute__((aligned(16))) _Float16 El[4][16 * KPAD];// per wave [q][key]

    int tid  = threadIdx.x;
    int lane = tid & 63;
    int w    = tid >> 6;
    int quad = lane >> 4;
    int l15  = lane & 15;
    int qt = blockIdx.x & 63;
    int bh = blockIdx.x >> 6;
    size_t base = (size_t)bh * (CC * DHH);
    int qbase = qt * 32 + w * 8;

    // one-time: Kl const region ([16]=1, rest 0) + zero ALL of El (rows 8..15 stay 0)
    for (int idx = tid; idx < 32 * 24; idx += 256) {
        int row = idx / 24, off = 16 + idx % 24;
        Kl[row * KPAD + off] = (off == 16) ? (_Float16)1.0f : (_Float16)0.0f;
    }
    {
        _Float16* Elf = &El[0][0];
        for (int idx = tid; idx < 4 * 16 * KPAD; idx += 256) Elf[idx] = (_Float16)0.0f;
    }

    // gelu poly constants (half2)
    h2 C0 = {(_Float16)c0, (_Float16)c0};
    h2 C1 = {(_Float16)c1, (_Float16)c1};
    h2 C2 = {(_Float16)c2, (_Float16)c2};
    h2 C3 = {(_Float16)c3, (_Float16)c3};
    h2 C4 = {(_Float16)c4, (_Float16)c4};
    const float ivu_f = 1.0f / (GCLAMP * GCLAMP);
    h2 IVU = {(_Float16)ivu_f, (_Float16)ivu_f};
    h2 LO = {(_Float16)(-GCLAMP), (_Float16)(-GCLAMP)};
    h2 HI = {(_Float16)GCLAMP, (_Float16)GCLAMP};

    // per-lane w2 for rows j = quad*4+r; fold 1/sqrt(16)*log2(e)*0.5 (gelu half)
    float w2h[4];
    #pragma unroll
    for (int r = 0; r < 4; ++r) w2h[r] = w2g[quad * 4 + r] * (0.25f * 1.44269504f * 0.5f);

    bool sel_hi = (lane & 16) != 0;                  // quads 1,3 -> sub1 value at store

    // W1k/W1qk slices are q-invariant: hoist to registers (per-lane j=l15, i=quad*8+jj)
    float wk[8], wqk[8];
    #pragma unroll
    for (int jj = 0; jj < 8; ++jj) {
        int i = (quad & 1) * 8 + jj;
        wk[jj]  = w1g[l15 * 48 + 16 + ((quad < 2) ? quad * 8 + jj : i)];
        wqk[jj] = w1g[l15 * 48 + 32 + ((quad < 2) ? quad * 8 + jj : i)];
    }

    // Bq A-frags: m=j=lane&15, kdim=i=quad*8+jj. quads0,1: W1qk[j][i]*q[i]+W1k[j][i];
    // quad2 jj=0: Aq[j]; else 0.
    half8 bq[8];
    {
        int j = l15;
        #pragma unroll
        for (int q = 0; q < 8; ++q) {
            const float* qv = Q + base + (size_t)(qbase + q) * 16;
            float aqv = A[base + (size_t)(qbase + q) * 16 + j];
            half8 v;
            #pragma unroll
            for (int jj = 0; jj < 8; ++jj) {
                float val;
                if (quad < 2) {
                    val = fmaf(wqk[jj], qv[quad * 8 + jj], wk[jj]);
                } else if (quad == 2 && jj == 0) {
                    val = aqv;
                } else {
                    val = 0.0f;
                }
                v[jj] = (_Float16)val;
            }
            bq[q] = v;
        }
    }

    half8 ones;
    #pragma unroll
    for (int jj = 0; jj < 8; ++jj) ones[jj] = (_Float16)1.0f;
    f32x4 Oc = {0.f, 0.f, 0.f, 0.f};
    f32x4 Dn = {0.f, 0.f, 0.f, 0.f};
    f32x4 zc = {0.f, 0.f, 0.f, 0.f};

    _Float16* Ew = El[w];

    // staging index map (fixed per thread)
    int skey = tid >> 3, sip = (tid & 7) * 2;        // K: thread -> (key, elem-pair)
    int vk0 = tid >> 4,          vd0 = tid & 15;     // V elem 0
    int vk1 = (tid + 256) >> 4,  vd1 = tid & 15;     // V elem 1

    // prefetch tile 0 into registers
    float2 kreg = *(const float2*)(K + base + (size_t)skey * 16 + sip);
    float  vreg0 = V[base + (size_t)vk0 * 16 + vd0];
    float  vreg1 = V[base + (size_t)vk1 * 16 + vd1];

    #pragma unroll 1
    for (int t0 = 0; t0 < CC; t0 += 32) {
        __syncthreads();                              // prior tile's LDS readers done
        Kl[skey * KPAD + sip]     = (_Float16)kreg.x;
        Kl[skey * KPAD + sip + 1] = (_Float16)kreg.y;
        Vt[vd0 * KPAD + vk0] = (_Float16)vreg0;
        Vt[vd1 * KPAD + vk1] = (_Float16)vreg1;
        {   // issue next tile's loads now; they fly during the compute below
            int tn = (t0 + 32 < CC) ? (t0 + 32) : 0;
            kreg  = *(const float2*)(K + base + (size_t)(tn + skey) * 16 + sip);
            vreg0 = V[base + (size_t)(tn + vk0) * 16 + vd0];
            vreg1 = V[base + (size_t)(tn + vk1) * 16 + vd1];
        }
        __syncthreads();                              // staging visible to all waves

        half8 bK0 = *(const half8*)&Kl[l15 * KPAD + quad * 8];
        half8 bK1 = *(const half8*)&Kl[(16 + l15) * KPAD + quad * 8];

        #pragma unroll
        for (int q = 0; q < 8; ++q) {
            f32x4 D0 = __builtin_amdgcn_mfma_f32_16x16x32_f16(bq[q], bK0, zc, 0, 0, 0);
            f32x4 D1 = __builtin_amdgcn_mfma_f32_16x16x32_f16(bq[q], bK1, zc, 0, 0, 0);
            float s0 = 0.0f, s1 = 0.0f;
            s0 = score_pair(D0[0], D0[1], w2h[0], w2h[1], s0, C0, C1, C2, C3, C4, IVU, LO, HI);
            s0 = score_pair(D0[2], D0[3], w2h[2], w2h[3], s0, C0, C1, C2, C3, C4, IVU, LO, HI);
            s1 = score_pair(D1[0], D1[1], w2h[0], w2h[1], s1, C0, C1, C2, C3, C4, IVU, LO, HI);
            s1 = score_pair(D1[2], D1[3], w2h[2], w2h[3], s1, C0, C1, C2, C3, C4, IVU, LO, HI);
            s0 += __shfl_xor(s0, 16, 64);
            s0 += __shfl_xor(s0, 32, 64);
            s1 += __shfl_xor(s1, 16, 64);
            s1 += __shfl_xor(s1, 32, 64);
            float uu = sel_hi ? s1 : s0;              // lanes 16..31 carry sub1
            float e = EXP2F(uu);                      // base-2 softmax (log2e folded in w2h)
            if (lane < 32) Ew[q * KPAD + lane] = (_Float16)e;
        }
        // E·V numerator + E·ones denominator (A rows 8..15 are zero -> inert)
        half8 aE = *(const half8*)&Ew[l15 * KPAD + quad * 8];
        half8 bV = *(const half8*)&Vt[l15 * KPAD + quad * 8];
        Oc = __builtin_amdgcn_mfma_f32_16x16x32_f16(aE, bV, Oc, 0, 0, 0);
        Dn = __builtin_amdgcn_mfma_f32_16x16x32_f16(aE, ones, Dn, 0, 0, 0);
    }

    // D layout: row(q)=quad*4+r, col(d)=lane&15; only rows 0..7 (quad<2) are real q's
    int b = bh >> 2, hh = bh & 3;
    if (quad < 2) {
        #pragma unroll
        for (int r = 0; r < 4; ++r) {
            int c = qbase + quad * 4 + r;
            AT[((size_t)(b * CC + c)) * DD + hh * 16 + l15] = Oc[r] / Dn[r];
        }
    }
}

// ---------------- fused post-attention: oproj + LN1 + FFN + LN2 (4 rows/block) ----------------
// Weights loaded once per thread and reused across 4 rows (4x less L2 traffic);
// each wave owns one row for the LN phases (no idle waves).
__global__ __launch_bounds__(256) void k_post(const float* __restrict__ AT,
                                              const float* __restrict__ ow, const float* __restrict__ ob,
                                              const float* __restrict__ g1, const float* __restrict__ be1,
                                              const float* __restrict__ f1w, const float* __restrict__ f1b,
                                              const float* __restrict__ f2w, const float* __restrict__ f2b,
                                              const float* __restrict__ g2, const float* __restrict__ be2,
                                              float* __restrict__ h) {
    int bc0 = blockIdx.x * 4;
    int t  = threadIdx.x;
    int j = t & 63, wv = t >> 6;
    __shared__ __attribute__((aligned(16))) float ar[4][64];
    __shared__ __attribute__((aligned(16))) float hln[4][64];
    __shared__ __attribute__((aligned(16))) float u[4][256];
    __shared__ float parts[4][4][64];                // [row][chunk][j]
    ar[wv][j] = AT[(size_t)(bc0 + wv) * 64 + j];
    __syncthreads();
    {   // out-proj partials: thread (wv=chunk, j=out) for all 4 rows
        float p0 = 0.f, p1 = 0.f, p2 = 0.f, p3 = 0.f;
        const float4* w4 = (const float4*)(ow + j * 64 + wv * 16);
        const float4* a0 = (const float4*)(ar[0] + wv * 16);
        const float4* a1 = (const float4*)(ar[1] + wv * 16);
        const float4* a2 = (const float4*)(ar[2] + wv * 16);
        const float4* a3 = (const float4*)(ar[3] + wv * 16);
        #pragma unroll
        for (int i = 0; i < 4; ++i) {
            float4 wvv = w4[i];
            float4 x0 = a0[i], x1 = a1[i], x2 = a2[i], x3 = a3[i];
            p0 = fmaf(x0.x, wvv.x, fmaf(x0.y, wvv.y, fmaf(x0.z, wvv.z, fmaf(x0.w, wvv.w, p0))));
            p1 = fmaf(x1.x, wvv.x, fmaf(x1.y, wvv.y, fmaf(x1.z, wvv.z, fmaf(x1.w, wvv.w, p1))));
            p2 = fmaf(x2.x, wvv.x, fmaf(x2.y, wvv.y, fmaf(x2.z, wvv.z, fmaf(x2.w, wvv.w, p2))));
            p3 = fmaf(x3.x, wvv.x, fmaf(x3.y, wvv.y, fmaf(x3.z, wvv.z, fmaf(x3.w, wvv.w, p3))));
        }
        parts[0][wv][j] = p0; parts[1][wv][j] = p1; parts[2][wv][j] = p2; parts[3][wv][j] = p3;
    }
    __syncthreads();
    {   // LN1: wave wv handles row wv
        float o = ob[j] + parts[wv][0][j] + parts[wv][1][j] + parts[wv][2][j] + parts[wv][3][j];
        float x = h[(size_t)(bc0 + wv) * 64 + j] + o;
        float m  = wave_sum64(x) * (1.0f / 64.0f);
        float dv = x - m;
        float vv = wave_sum64(dv * dv) * (1.0f / 64.0f);
        float r  = __builtin_amdgcn_rsqf(vv + 1e-5f);
        hln[wv][j] = fmaf(dv * r, g1[j], be1[j]);
    }
    __syncthreads();
    {   // FFN1: thread t computes hidden unit t for all 4 rows (weights loaded once)
        float b = f1b[t];
        float a0 = b, a1 = b, a2 = b, a3 = b;
        const float4* w4 = (const float4*)(f1w + t * 64);
        const float4* h0 = (const float4*)hln[0];
        const float4* h1 = (const float4*)hln[1];
        const float4* h2p = (const float4*)hln[2];
        const float4* h3 = (const float4*)hln[3];
        #pragma unroll
        for (int i = 0; i < 16; ++i) {
            float4 wvv = w4[i];
            float4 x0 = h0[i], x1 = h1[i], x2 = h2p[i], x3 = h3[i];
            a0 = fmaf(x0.x, wvv.x, fmaf(x0.y, wvv.y, fmaf(x0.z, wvv.z, fmaf(x0.w, wvv.w, a0))));
            a1 = fmaf(x1.x, wvv.x, fmaf(x1.y, wvv.y, fmaf(x1.z, wvv.z, fmaf(x1.w, wvv.w, a1))));
            a2 = fmaf(x2.x, wvv.x, fmaf(x2.y, wvv.y, fmaf(x2.z, wvv.z, fmaf(x2.w, wvv.w, a2))));
            a3 = fmaf(x3.x, wvv.x, fmaf(x3.y, wvv.y, fmaf(x3.z, wvv.z, fmaf(x3.w, wvv.w, a3))));
        }
        u[0][t] = gelu_f(a0); u[1][t] = gelu_f(a1); u[2][t] = gelu_f(a2); u[3][t] = gelu_f(a3);
    }
    __syncthreads();
    {   // FFN2 partials
        float p0 = 0.f, p1 = 0.f, p2 = 0.f, p3 = 0.f;
        const float4* w4 = (const float4*)(f2w + j * 256 + wv * 64);
        const float4* u0 = (const float4*)(u[0] + wv * 64);
        const float4* u1 = (const float4*)(u[1] + wv * 64);
        const float4* u2 = (const float4*)(u[2] + wv * 64);
        const float4* u3 = (const float4*)(u[3] + wv * 64);
        #pragma unroll
        for (int i = 0; i < 16; ++i) {
            float4 wvv = w4[i];
            float4 x0 = u0[i], x1 = u1[i], x2 = u2[i], x3 = u3[i];
            p0 = fmaf(x0.x, wvv.x, fmaf(x0.y, wvv.y, fmaf(x0.z, wvv.z, fmaf(x0.w, wvv.w, p0))));
            p1 = fmaf(x1.x, wvv.x, fmaf(x1.y, wvv.y, fmaf(x1.z, wvv.z, fmaf(x1.w, wvv.w, p1))));
            p2 = fmaf(x2.x, wvv.x, fmaf(x2.y, wvv.y, fmaf(x2.z, wvv.z, fmaf(x2.w, wvv.w, p2))));
            p3 = fmaf(x3.x, wvv.x, fmaf(x3.y, wvv.y, fmaf(x3.z, wvv.z, fmaf(x3.w, wvv.w, p3))));
        }
        parts[0][wv][j] = p0; parts[1][wv][j] = p1; parts[2][wv][j] = p2; parts[3][wv][j] = p3;
    }
    __syncthreads();
    {   // LN2: wave wv handles row wv
        float o = f2b[j] + parts[wv][0][j] + parts[wv][1][j] + parts[wv][2][j] + parts[wv][3][j];
        float x = hln[wv][j] + o;
        float m  = wave_sum64(x) * (1.0f / 64.0f);
        float dv = x - m;
        float vv = wave_sum64(dv * dv) * (1.0f / 64.0f);
        float r  = __builtin_amdgcn_rsqf(vv + 1e-5f);
        h[(size_t)(bc0 + wv) * 64 + j] = fmaf(dv * r, g2[j], be2[j]);
    }
}

// ---------------- task-query readout ----------------
__global__ __launch_bounds__(256) void k_readout(const float* __restrict__ h,
                                                 const float* __restrict__ tq,
                                                 const float* __restrict__ hw, const float* __restrict__ hb,
                                                 float* __restrict__ out) {
    int b = blockIdx.x;
    int t = threadIdx.x;
    __shared__ float ebuf[2048];
    __shared__ float tqs[64];
    __shared__ float sred[256];
    __shared__ float red[4][64];
    if (t < 64) tqs[t] = tq[t];
    __syncthreads();
    float ss = 0.0f;
    for (int c = t; c < CC; c += 256) {
        const float* hrow = h + ((size_t)b * CC + c) * 64;
        float s = 0.0f;
        #pragma unroll
        for (int d = 0; d < 64; ++d) s = fmaf(hrow[d], tqs[d], s);
        float e = __expf(s * 0.125f);                 // scores ~ +-0.1: max-free safe
        ebuf[c] = e; ss += e;
    }
    sred[t] = ss;
    __syncthreads();
    for (int o = 128; o; o >>= 1) {
        if (t < o) sred[t] += sred[t + o];
        __syncthreads();
    }
    float inv = 1.0f / sred[0];
    int d = t & 63, ch = t >> 6;
    float p = 0.0f;
    for (int c = ch * 512; c < ch * 512 + 512; ++c)
        p = fmaf(ebuf[c], h[((size_t)b * CC + c) * 64 + d], p);
    red[ch][d] = p;
    __syncthreads();
    if (t < 64) red[0][t] = (red[0][t] + red[1][t] + red[2][t] + red[3][t]) * inv;
    __syncthreads();
    if (t < 10) {
        float o = hb[t];
        #pragma unroll
        for (int d2 = 0; d2 < 64; ++d2) o = fmaf(red[0][d2], hw[t * 64 + d2], o);
        out[b * 10 + t] = o;
    }
}

extern "C" void kernel_launch(void* const* d_in, const int* in_sizes, int n_in,
                              void* d_out, int out_size, void* d_ws, size_t ws_size,
                              hipStream_t stream) {
    (void)in_sizes; (void)n_in; (void)out_size; (void)ws_size;
    const float* x    = (const float*)d_in[0];
    const float* role = (const float*)d_in[1];
    const float* fw   = (const float*)d_in[2];
    const float* qw   = (const float*)d_in[3];
    const float* qb   = (const float*)d_in[4];
    const float* kw   = (const float*)d_in[5];
    const float* kb   = (const float*)d_in[6];
    const float* vw   = (const float*)d_in[7];
    const float* vb   = (const float*)d_in[8];
    const float* w1   = (const float*)d_in[9];
    const float* b1   = (const float*)d_in[10];
    const float* w2   = (const float*)d_in[11];
    // d_in[12] = b2: softmax-shift-invariant, dropped
    const float* ow   = (const float*)d_in[13];
    const float* ob   = (const float*)d_in[14];
    const float* g1   = (const float*)d_in[15];
    const float* be1  = (const float*)d_in[16];
    const float* f1w  = (const float*)d_in[17];
    const float* f1b  = (const float*)d_in[18];
    const float* f2w  = (const float*)d_in[19];
    const float* f2b  = (const float*)d_in[20];
    const float* g2   = (const float*)d_in[21];
    const float* be2  = (const float*)d_in[22];
    const float* tq   = (const float*)d_in[23];
    const float* hw   = (const float*)d_in[24];
    const float* hb   = (const float*)d_in[25];

    float cf[5];
    fit_gelu_poly(cf);                               // deterministic per call (~us, host-only)

    float* ws   = (float*)d_ws;
    const size_t M = 1048576;                        // B*C*D
    float* H    = ws;
    float* Q    = ws + 1 * M;
    float* K    = ws + 2 * M;
    float* V    = ws + 3 * M;
    float* Abuf = ws + 4 * M;
    float* AT   = ws + 5 * M;

    k_binding<<<4096, 256, 0, stream>>>(x, role, fw, H);
    for (int l = 0; l < LL; ++l) {
        k_qkv<<<4096, 256, 0, stream>>>(H, qw + l * 4096, qb + l * 64, kw + l * 4096, kb + l * 64,
                                        vw + l * 4096, vb + l * 64, w1 + l * 768, b1 + l * 16,
                                        Q, K, V, Abuf);
        k_attn<<<2048, 256, 0, stream>>>(Q, K, V, Abuf, w1 + l * 768, w2 + l * 16, AT,
                                         cf[0], cf[1], cf[2], cf[3], cf[4]);
        k_post<<<4096, 256, 0, stream>>>(AT, ow + l * 4096, ob + l * 64, g1 + l * 64, be1 + l * 64,
                                         f1w + l * 16384, f1b + l * 256, f2w + l * 16384,
                                         f2b + l * 64, g2 + l * 64, be2 + l * 64, H);
    }
    k_readout<<<8, 256, 0, stream>>>(H, tq, hw, hb, (float*)d_out);
}